// Round 7
// baseline (495.454 us; speedup 1.0000x reference)
//
#include <hip/hip_runtime.h>
#include <hip/hip_bf16.h>

#define BATCH 2
#define LSEQ 4096
#define DM 256
#define NS 16
#define BL (BATCH*LSEQ)
#define CHUNK 32
#define NCHUNK (LSEQ/CHUNK)     // 128
#define NSEQ (4*BATCH)          // 8 lookback sequences (dq, b)
#define MS_STRIDE 260
#define LOG2E 1.4426950408889634f

typedef _Float16 f16x8 __attribute__((ext_vector_type(8)));
typedef _Float16 f16x4 __attribute__((ext_vector_type(4)));
typedef float f32x4 __attribute__((ext_vector_type(4)));
typedef unsigned long long ull;

__device__ __forceinline__ float softplus_f(float z){
    return fmaxf(z, 0.0f) + log1pf(__expf(-fabsf(z)));
}
__device__ __forceinline__ float gelu_f(float x){
    float u = 0.7978845608028654f*(x + 0.044715f*x*x*x);
    float e = __builtin_amdgcn_exp2f(2.0f*LOG2E*u);
    float th = 1.0f - 2.0f*__builtin_amdgcn_rcpf(e + 1.0f);
    return 0.5f*x*(1.0f + th);
}
__device__ __forceinline__ ull pack_ab(float a, float b){
    return ((ull)__float_as_uint(b) << 32) | (ull)__float_as_uint(a);
}

// Pack weights (fp32 -> f16) into MFMA B-fragment order.
__global__ __launch_bounds__(256) void pack_w_k(const float* __restrict__ Wd,
                         const float* __restrict__ WB,
                         const float* __restrict__ WC,
                         const float* __restrict__ Wm,
                         _Float16* __restrict__ pd0, _Float16* __restrict__ pm0,
                         _Float16* __restrict__ pd1, _Float16* __restrict__ pm1){
    int cfg = blockIdx.y;
    int layer = cfg >> 1;
    int isMix = cfg & 1;
    int count = isMix ? 16*8*64 : 18*8*64;
    int t = blockIdx.x*256 + threadIdx.x;
    if (t >= count) return;
    int lane = t & 63;
    int ks   = (t >> 6) & 7;
    int nt16 = t >> 9;
    int col  = nt16*16 + (lane & 15);
    int kb   = ks*32 + ((lane >> 4) << 3);
    const float* Wd_l = Wd + (size_t)layer*DM*DM;
    const float* WB_l = WB + (size_t)layer*DM*NS;
    const float* WC_l = WC + (size_t)layer*DM*NS;
    const float* Wm_l = Wm + (size_t)layer*DM*DM;
    f16x8 v;
    #pragma unroll
    for (int i=0;i<8;++i){
        float s;
        if (isMix)          s = Wm_l[(size_t)(kb+i)*DM + col];
        else if (col < 256) s = Wd_l[(size_t)(kb+i)*DM + col];
        else if (col < 272) s = WB_l[(size_t)(kb+i)*NS + (col-256)];
        else                s = WC_l[(size_t)(kb+i)*NS + (col-272)];
        v[i] = (_Float16)s;
    }
    _Float16* dst = isMix ? (layer ? pm1 : pm0) : (layer ? pd1 : pd0);
    ((f16x8*)dst)[t] = v;
}

// Fused RMSNorm + dtbc GEMM. Block = 32 rows, 576 threads (9 MFMA waves).
__global__ __launch_bounds__(576) void fused_pre(const float* __restrict__ xin,
                          const _Float16* __restrict__ wp,
                          const float* __restrict__ bd,
                          float* __restrict__ xn,
                          float* __restrict__ dt,
                          float* __restrict__ Bm,
                          float* __restrict__ Cm){
    __shared__ _Float16 xs[32*32*8];   // 16 KB
    int t = threadIdx.x;
    int row0 = blockIdx.x*32;
    if (t < 512){
        int r = t >> 4;
        int cb = t & 15;
        const float4* src = (const float4*)(xin + (size_t)(row0+r)*DM);
        float4 v[4];
        float ss = 0.0f;
        #pragma unroll
        for (int j=0;j<4;++j){
            v[j] = src[cb + 16*j];
            ss += v[j].x*v[j].x + v[j].y*v[j].y + v[j].z*v[j].z + v[j].w*v[j].w;
        }
        ss += __shfl_xor(ss, 1, 64);
        ss += __shfl_xor(ss, 2, 64);
        ss += __shfl_xor(ss, 4, 64);
        ss += __shfl_xor(ss, 8, 64);
        float s = rsqrtf(ss*(1.0f/DM) + 1.1920929e-07f);
        float4* xout = (float4*)(xn + (size_t)(row0+r)*DM);
        #pragma unroll
        for (int j=0;j<4;++j){
            int c4 = cb + 16*j;
            float4 o; o.x=v[j].x*s; o.y=v[j].y*s; o.z=v[j].z*s; o.w=v[j].w*s;
            xout[c4] = o;
            int slot = c4 >> 1;
            int j0   = (c4 & 1)*4;
            f16x4 hv; hv[0]=(_Float16)o.x; hv[1]=(_Float16)o.y;
            hv[2]=(_Float16)o.z; hv[3]=(_Float16)o.w;
            *(f16x4*)&xs[((size_t)r*32 + (slot ^ (r & 7)))*8 + j0] = hv;
        }
    }
    __syncthreads();
    int w    = t >> 6;
    int lane = t & 63;
    const f16x8* wpb = (const f16x8*)wp;
    int rl = lane & 15;
    int kg = lane >> 4;
    f32x4 acc[2][2] = {};
    #pragma unroll
    for (int ks=0; ks<8; ++ks){
        int s0 = kg + ks*4;
        f16x8 a0 = *(const f16x8*)&xs[((size_t)(rl     )*32 + (s0 ^ (rl & 7)))*8];
        f16x8 a1 = *(const f16x8*)&xs[((size_t)(rl + 16)*32 + (s0 ^ (rl & 7)))*8];
        f16x8 b0 = wpb[((w*2    )*8 + ks)*64 + lane];
        f16x8 b1 = wpb[((w*2 + 1)*8 + ks)*64 + lane];
        acc[0][0] = __builtin_amdgcn_mfma_f32_16x16x32_f16(a0,b0,acc[0][0],0,0,0);
        acc[0][1] = __builtin_amdgcn_mfma_f32_16x16x32_f16(a0,b1,acc[0][1],0,0,0);
        acc[1][0] = __builtin_amdgcn_mfma_f32_16x16x32_f16(a1,b0,acc[1][0],0,0,0);
        acc[1][1] = __builtin_amdgcn_mfma_f32_16x16x32_f16(a1,b1,acc[1][1],0,0,0);
    }
    int c0 = w*32 + (lane & 15);
    int rb = row0 + ((lane >> 4) << 2);
    if (w < 8){
        float bias0 = bd[c0], bias1 = bd[c0 + 16];
        #pragma unroll
        for (int mi=0; mi<2; ++mi){
            #pragma unroll
            for (int r=0; r<4; ++r){
                int grow = rb + mi*16 + r;
                dt[(size_t)grow*DM + c0]      = softplus_f(acc[mi][0][r] + bias0);
                dt[(size_t)grow*DM + c0 + 16] = softplus_f(acc[mi][1][r] + bias1);
            }
        }
    } else {
        int n = lane & 15;
        #pragma unroll
        for (int mi=0; mi<2; ++mi){
            #pragma unroll
            for (int r=0; r<4; ++r){
                int grow = rb + mi*16 + r;
                Bm[(size_t)grow*NS + n] = acc[mi][0][r];
                Cm[(size_t)grow*NS + n] = acc[mi][1][r];
            }
        }
    }
}

// Fused mix-GEMM + RMSNorm + next-layer dtbc-GEMM. 576 threads, 32 rows/block.
__global__ __launch_bounds__(576) void fused_mid(const _Float16* __restrict__ yh,
                          const _Float16* __restrict__ wpm,
                          const float* __restrict__ bm,
                          const _Float16* __restrict__ wpd,
                          const float* __restrict__ bd,
                          float* __restrict__ xn,
                          float* __restrict__ dt,
                          float* __restrict__ Bm,
                          float* __restrict__ Cm){
    __shared__ float ms[32*MS_STRIDE];   // 32.5 KB mix output
    __shared__ _Float16 xs[32*32*8];     // 16 KB f16 fragments
    int t = threadIdx.x;
    int w = t >> 6, lane = t & 63;
    int row0 = blockIdx.x*32;
    if (w < 8){
        const f16x8* ah  = (const f16x8*)yh;
        const f16x8* wpb = (const f16x8*)wpm;
        size_t a0i = (size_t)(row0 + (lane & 15))*32 + (lane >> 4);
        f32x4 acc[2][2] = {};
        #pragma unroll
        for (int ks=0; ks<8; ++ks){
            f16x8 a0 = ah[a0i + ks*4];
            f16x8 a1 = ah[a0i + 512 + ks*4];
            f16x8 b0 = wpb[((w*2    )*8 + ks)*64 + lane];
            f16x8 b1 = wpb[((w*2 + 1)*8 + ks)*64 + lane];
            acc[0][0] = __builtin_amdgcn_mfma_f32_16x16x32_f16(a0,b0,acc[0][0],0,0,0);
            acc[0][1] = __builtin_amdgcn_mfma_f32_16x16x32_f16(a0,b1,acc[0][1],0,0,0);
            acc[1][0] = __builtin_amdgcn_mfma_f32_16x16x32_f16(a1,b0,acc[1][0],0,0,0);
            acc[1][1] = __builtin_amdgcn_mfma_f32_16x16x32_f16(a1,b1,acc[1][1],0,0,0);
        }
        int c0 = w*32 + (lane & 15);
        int rb = (lane >> 4) << 2;
        float bias0 = bm[c0], bias1 = bm[c0 + 16];
        #pragma unroll
        for (int mi=0; mi<2; ++mi){
            #pragma unroll
            for (int r=0; r<4; ++r){
                int lr = rb + mi*16 + r;
                ms[lr*MS_STRIDE + c0]      = acc[mi][0][r] + bias0;
                ms[lr*MS_STRIDE + c0 + 16] = acc[mi][1][r] + bias1;
            }
        }
    }
    __syncthreads();
    if (t < 512){
        int r = t >> 4;
        int cb = t & 15;
        float4 v[4];
        float ss = 0.0f;
        #pragma unroll
        for (int j=0;j<4;++j){
            v[j] = *(const float4*)&ms[r*MS_STRIDE + (cb + 16*j)*4];
            ss += v[j].x*v[j].x + v[j].y*v[j].y + v[j].z*v[j].z + v[j].w*v[j].w;
        }
        ss += __shfl_xor(ss, 1, 64);
        ss += __shfl_xor(ss, 2, 64);
        ss += __shfl_xor(ss, 4, 64);
        ss += __shfl_xor(ss, 8, 64);
        float s = rsqrtf(ss*(1.0f/DM) + 1.1920929e-07f);
        float4* xout = (float4*)(xn + (size_t)(row0+r)*DM);
        #pragma unroll
        for (int j=0;j<4;++j){
            int c4 = cb + 16*j;
            float4 o; o.x=v[j].x*s; o.y=v[j].y*s; o.z=v[j].z*s; o.w=v[j].w*s;
            xout[c4] = o;
            int slot = c4 >> 1;
            int j0   = (c4 & 1)*4;
            f16x4 hv; hv[0]=(_Float16)o.x; hv[1]=(_Float16)o.y;
            hv[2]=(_Float16)o.z; hv[3]=(_Float16)o.w;
            *(f16x4*)&xs[((size_t)r*32 + (slot ^ (r & 7)))*8 + j0] = hv;
        }
    }
    __syncthreads();
    {
        const f16x8* wpb = (const f16x8*)wpd;
        int rl = lane & 15;
        int kg = lane >> 4;
        f32x4 acc[2][2] = {};
        #pragma unroll
        for (int ks=0; ks<8; ++ks){
            int s0 = kg + ks*4;
            f16x8 a0 = *(const f16x8*)&xs[((size_t)(rl     )*32 + (s0 ^ (rl & 7)))*8];
            f16x8 a1 = *(const f16x8*)&xs[((size_t)(rl + 16)*32 + (s0 ^ (rl & 7)))*8];
            f16x8 b0 = wpb[((w*2    )*8 + ks)*64 + lane];
            f16x8 b1 = wpb[((w*2 + 1)*8 + ks)*64 + lane];
            acc[0][0] = __builtin_amdgcn_mfma_f32_16x16x32_f16(a0,b0,acc[0][0],0,0,0);
            acc[0][1] = __builtin_amdgcn_mfma_f32_16x16x32_f16(a0,b1,acc[0][1],0,0,0);
            acc[1][0] = __builtin_amdgcn_mfma_f32_16x16x32_f16(a1,b0,acc[1][0],0,0,0);
            acc[1][1] = __builtin_amdgcn_mfma_f32_16x16x32_f16(a1,b1,acc[1][1],0,0,0);
        }
        int c0 = w*32 + (lane & 15);
        int rb = row0 + ((lane >> 4) << 2);
        if (w < 8){
            float bias0 = bd[c0], bias1 = bd[c0 + 16];
            #pragma unroll
            for (int mi=0; mi<2; ++mi){
                #pragma unroll
                for (int r=0; r<4; ++r){
                    int grow = rb + mi*16 + r;
                    dt[(size_t)grow*DM + c0]      = softplus_f(acc[mi][0][r] + bias0);
                    dt[(size_t)grow*DM + c0 + 16] = softplus_f(acc[mi][1][r] + bias1);
                }
            }
        } else {
            int n = lane & 15;
            #pragma unroll
            for (int mi=0; mi<2; ++mi){
                #pragma unroll
                for (int r=0; r<4; ++r){
                    int grow = rb + mi*16 + r;
                    Bm[(size_t)grow*NS + n] = acc[mi][0][r];
                    Cm[(size_t)grow*NS + n] = acc[mi][1][r];
                }
            }
        }
    }
}

// Fused final mix-GEMM + final RMSNorm -> out. 512 threads, 32 rows/block.
__global__ __launch_bounds__(512) void fused_out(const _Float16* __restrict__ yh,
                          const _Float16* __restrict__ wpm,
                          const float* __restrict__ bm,
                          float* __restrict__ out){
    __shared__ float ms[32*MS_STRIDE];
    int t = threadIdx.x;
    int w = t >> 6, lane = t & 63;
    int row0 = blockIdx.x*32;
    {
        const f16x8* ah  = (const f16x8*)yh;
        const f16x8* wpb = (const f16x8*)wpm;
        size_t a0i = (size_t)(row0 + (lane & 15))*32 + (lane >> 4);
        f32x4 acc[2][2] = {};
        #pragma unroll
        for (int ks=0; ks<8; ++ks){
            f16x8 a0 = ah[a0i + ks*4];
            f16x8 a1 = ah[a0i + 512 + ks*4];
            f16x8 b0 = wpb[((w*2    )*8 + ks)*64 + lane];
            f16x8 b1 = wpb[((w*2 + 1)*8 + ks)*64 + lane];
            acc[0][0] = __builtin_amdgcn_mfma_f32_16x16x32_f16(a0,b0,acc[0][0],0,0,0);
            acc[0][1] = __builtin_amdgcn_mfma_f32_16x16x32_f16(a0,b1,acc[0][1],0,0,0);
            acc[1][0] = __builtin_amdgcn_mfma_f32_16x16x32_f16(a1,b0,acc[1][0],0,0,0);
            acc[1][1] = __builtin_amdgcn_mfma_f32_16x16x32_f16(a1,b1,acc[1][1],0,0,0);
        }
        int c0 = w*32 + (lane & 15);
        int rb = (lane >> 4) << 2;
        float bias0 = bm[c0], bias1 = bm[c0 + 16];
        #pragma unroll
        for (int mi=0; mi<2; ++mi){
            #pragma unroll
            for (int r=0; r<4; ++r){
                int lr = rb + mi*16 + r;
                ms[lr*MS_STRIDE + c0]      = acc[mi][0][r] + bias0;
                ms[lr*MS_STRIDE + c0 + 16] = acc[mi][1][r] + bias1;
            }
        }
    }
    __syncthreads();
    {
        int r = t >> 4;
        int cb = t & 15;
        float4 v[4];
        float ss = 0.0f;
        #pragma unroll
        for (int j=0;j<4;++j){
            v[j] = *(const float4*)&ms[r*MS_STRIDE + (cb + 16*j)*4];
            ss += v[j].x*v[j].x + v[j].y*v[j].y + v[j].z*v[j].z + v[j].w*v[j].w;
        }
        ss += __shfl_xor(ss, 1, 64);
        ss += __shfl_xor(ss, 2, 64);
        ss += __shfl_xor(ss, 4, 64);
        ss += __shfl_xor(ss, 8, 64);
        float s = rsqrtf(ss*(1.0f/DM) + 1.1920929e-07f);
        float4* xout = (float4*)(out + (size_t)(row0+r)*DM);
        #pragma unroll
        for (int j=0;j<4;++j){
            float4 o = v[j];
            o.x*=s; o.y*=s; o.z*=s; o.w*=s;
            xout[cb + 16*j] = o;
        }
    }
}

// Single-kernel chunked scan with decoupled lookback.
// grid (NCHUNK, DM/64, BATCH) x 256 threads; thread = (d, n-quad).
// Publishes per-chunk (A,B) packed in 8B words via device-scope atomics.
__global__ __launch_bounds__(256) void scan_lb(const float* __restrict__ xn,
                        const float* __restrict__ dt,
                        const float* __restrict__ Bmv,
                        const float* __restrict__ Cmv,
                        const float* __restrict__ A,
                        const float* __restrict__ Dsk,
                        ull* __restrict__ agg,
                        ull* __restrict__ incl,
                        int* __restrict__ flags,
                        _Float16* __restrict__ yh,
                        int genA, int genI){
    __shared__ float sdt[CHUNK][64];
    __shared__ float sxn[CHUNK][64];
    __shared__ float4 bs[CHUNK*4], cs[CHUNK*4];
    __shared__ int relay;
    int tid = threadIdx.x;
    int c = blockIdx.x, dq = blockIdx.y, b = blockIdx.z;
    int seq = dq + 4*b;
    int dl = tid >> 2, nq = tid & 3;
    int d  = dq*64 + dl;
    int row0 = b*LSEQ + c*CHUNK;
    // stage dt/xn chunk slice (32 t x 64 d) into LDS, coalesced
    {
        int fi = tid;           // float4 index 0..255
        int t0 = fi >> 4, cg = fi & 15;
        *(float4*)&sdt[t0][cg*4]    = *(const float4*)(dt + (size_t)(row0+t0)*DM + dq*64 + cg*4);
        *(float4*)&sxn[t0][cg*4]    = *(const float4*)(xn + (size_t)(row0+t0)*DM + dq*64 + cg*4);
        int t1 = t0 + 16;
        *(float4*)&sdt[t1][cg*4]    = *(const float4*)(dt + (size_t)(row0+t1)*DM + dq*64 + cg*4);
        *(float4*)&sxn[t1][cg*4]    = *(const float4*)(xn + (size_t)(row0+t1)*DM + dq*64 + cg*4);
    }
    if (tid < CHUNK*4){
        bs[tid] = ((const float4*)(Bmv + (size_t)row0*NS))[tid];
        cs[tid] = ((const float4*)(Cmv + (size_t)row0*NS))[tid];
    }
    float4 Alg = ((const float4*)(A + (size_t)d*NS))[nq];
    float alg[4] = {Alg.x*LOG2E, Alg.y*LOG2E, Alg.z*LOG2E, Alg.w*LOG2E};
    float dsk = Dsk[d];
    __syncthreads();
    // ---- local chunk summary ----
    float Ap[4] = {1,1,1,1}, Bp[4] = {0,0,0,0};
    #pragma unroll 4
    for (int tt=0; tt<CHUNK; ++tt){
        float dtv = sdt[tt][dl];
        float xv  = sxn[tt][dl];
        float dtx = dtv*xv;
        float4 bq = bs[tt*4 + nq];
        float bv[4] = {bq.x, bq.y, bq.z, bq.w};
        #pragma unroll
        for (int j=0;j<4;++j){
            float a = __builtin_amdgcn_exp2f(dtv*alg[j]);
            Ap[j] *= a;
            Bp[j] = fmaf(a, Bp[j], dtx*bv[j]);
        }
    }
    // ---- publish aggregate ----
    size_t base = ((size_t)(seq*NCHUNK + c))*1024 + (size_t)dl*16 + nq*4;
    #pragma unroll
    for (int j=0;j<4;++j)
        __hip_atomic_store(&agg[base+j], pack_ab(Ap[j], Bp[j]),
                           __ATOMIC_RELAXED, __HIP_MEMORY_SCOPE_AGENT);
    __syncthreads();   // drains each wave's stores (vmcnt 0 before barrier)
    if (tid == 0)
        __hip_atomic_store(&flags[seq*NCHUNK + c], genA,
                           __ATOMIC_RELEASE, __HIP_MEMORY_SCOPE_AGENT);
    // ---- lookback: build exclusive prefix map (Ae,Be) of chunks [0..c-1] ----
    float Ae[4] = {1,1,1,1}, Be[4] = {0,0,0,0};
    int k = c - 1;
    while (k >= 0){
        __syncthreads();
        if (tid == 0){
            int f;
            do {
                f = __hip_atomic_load(&flags[seq*NCHUNK + k],
                                      __ATOMIC_RELAXED, __HIP_MEMORY_SCOPE_AGENT);
                if (f != genA && f != genI) __builtin_amdgcn_s_sleep(2);
            } while (f != genA && f != genI);
            (void)__hip_atomic_load(&flags[seq*NCHUNK + k],
                                    __ATOMIC_ACQUIRE, __HIP_MEMORY_SCOPE_AGENT);
            relay = f;
        }
        __syncthreads();
        int f = relay;
        const ull* src = (f == genI) ? incl : agg;
        size_t kb = ((size_t)(seq*NCHUNK + k))*1024 + (size_t)dl*16 + nq*4;
        #pragma unroll
        for (int j=0;j<4;++j){
            ull wv = __hip_atomic_load(&src[kb+j],
                                       __ATOMIC_RELAXED, __HIP_MEMORY_SCOPE_AGENT);
            float Ak = __uint_as_float((unsigned)wv);
            float Bk = __uint_as_float((unsigned)(wv >> 32));
            Be[j] = fmaf(Ae[j], Bk, Be[j]);
            Ae[j] *= Ak;
        }
        if (f == genI) break;
        --k;
    }
    // ---- publish inclusive = own ∘ exclusive ----
    #pragma unroll
    for (int j=0;j<4;++j){
        float Ai = Ap[j]*Ae[j];
        float Bi = fmaf(Ap[j], Be[j], Bp[j]);
        __hip_atomic_store(&incl[base+j], pack_ab(Ai, Bi),
                           __ATOMIC_RELAXED, __HIP_MEMORY_SCOPE_AGENT);
    }
    __syncthreads();
    if (tid == 0)
        __hip_atomic_store(&flags[seq*NCHUNK + c], genI,
                           __ATOMIC_RELEASE, __HIP_MEMORY_SCOPE_AGENT);
    // ---- replay with h_in = Be; y = h·C + D_skip*x; gelu -> f16 ----
    float h[4] = {Be[0], Be[1], Be[2], Be[3]};
    #pragma unroll 4
    for (int tt=0; tt<CHUNK; ++tt){
        float dtv = sdt[tt][dl];
        float xv  = sxn[tt][dl];
        float dtx = dtv*xv;
        float4 bq = bs[tt*4 + nq];
        float4 cq = cs[tt*4 + nq];
        float bv[4] = {bq.x, bq.y, bq.z, bq.w};
        float cv[4] = {cq.x, cq.y, cq.z, cq.w};
        float p = 0.0f;
        #pragma unroll
        for (int j=0;j<4;++j){
            float a = __builtin_amdgcn_exp2f(dtv*alg[j]);
            h[j] = fmaf(a, h[j], dtx*bv[j]);
            p = fmaf(h[j], cv[j], p);
        }
        p += __shfl_xor(p, 1, 64);
        p += __shfl_xor(p, 2, 64);
        if (nq == 0){
            float yv = p + dsk*xv;
            yh[(size_t)(row0+tt)*DM + d] = (_Float16)gelu_f(yv);
        }
    }
}

extern "C" void kernel_launch(void* const* d_in, const int* in_sizes, int n_in,
                              void* d_out, int out_size, void* d_ws, size_t ws_size,
                              hipStream_t stream) {
    const float* x  = (const float*)d_in[0];
    const float* A  = (const float*)d_in[1];
    const float* Wd = (const float*)d_in[2];
    const float* bd = (const float*)d_in[3];
    const float* WB = (const float*)d_in[4];
    const float* WC = (const float*)d_in[5];
    const float* Ds = (const float*)d_in[6];
    const float* Wm = (const float*)d_in[7];
    const float* bm = (const float*)d_in[8];
    float* out = (float*)d_out;

    const size_t BSZ = (size_t)BL*DM;            // 2,097,152 floats
    const size_t CHW = (size_t)NSEQ*NCHUNK*1024; // 1,048,576 ull words
    float* ws  = (float*)d_ws;
    float* b0  = ws;                 // xn
    float* b1  = b0  + BSZ;          // dt
    float* Bmb = b1  + BSZ;
    float* Cmb = Bmb + (size_t)BL*NS;
    ull*  aggb = (ull*)(Cmb + (size_t)BL*NS);
    ull*  incb = aggb + CHW;
    int*  flags = (int*)(incb + CHW);            // 1024 ints
    _Float16* packs = (_Float16*)(flags + 1024);
    _Float16* pd0 = packs;
    _Float16* pd1 = pd0 + 73728;
    _Float16* pm0 = pd1 + 73728;
    _Float16* pm1 = pm0 + 65536;
    _Float16* yh  = pm1 + 65536;                 // BL*DM f16

    dim3 gscan(NCHUNK, DM/64, BATCH);

    hipMemsetAsync(flags, 0, NSEQ*NCHUNK*sizeof(int), stream);
    pack_w_k<<<dim3(36,4), 256, 0, stream>>>(Wd, WB, WC, Wm, pd0, pm0, pd1, pm1);

    const float* A1  = A  + (size_t)DM*NS;
    const float* bd1 = bd + DM;
    const float* Ds1 = Ds + DM;
    const float* bm1 = bm + DM;

    // ---- layer 0 ----
    fused_pre<<<BL/32, 576, 0, stream>>>(x, pd0, bd, b0, b1, Bmb, Cmb);
    scan_lb<<<gscan, 256, 0, stream>>>(b0, b1, Bmb, Cmb, A, Ds,
                                       aggb, incb, flags, yh, 1, 2);
    // ---- mix(L0) + rmsnorm + dtbc(L1) ----
    fused_mid<<<BL/32, 576, 0, stream>>>(yh, pm0, bm, pd1, bd1, b0, b1, Bmb, Cmb);
    // ---- layer 1 scan (fresh flag generations; no reset needed) ----
    scan_lb<<<gscan, 256, 0, stream>>>(b0, b1, Bmb, Cmb, A1, Ds1,
                                       aggb, incb, flags, yh, 3, 4);
    // ---- mix(L1) + final rmsnorm ----
    fused_out<<<BL/32, 512, 0, stream>>>(yh, pm1, bm1, out);
}

// Round 8
// 220.970 us; speedup vs baseline: 2.2422x; 2.2422x over previous
//
#include <hip/hip_runtime.h>
#include <hip/hip_bf16.h>

#define BATCH 2
#define LSEQ 4096
#define DM 256
#define NS 16
#define BL (BATCH*LSEQ)
#define CHUNK 32
#define NCHUNK (LSEQ/CHUNK)     // 128
#define NCHAIN (BATCH*DM*NS)    // 8192
#define MS_STRIDE 260
#define LOG2E 1.4426950408889634f

typedef _Float16 f16x8 __attribute__((ext_vector_type(8)));
typedef _Float16 f16x4 __attribute__((ext_vector_type(4)));
typedef float f32x4 __attribute__((ext_vector_type(4)));

__device__ __forceinline__ float softplus_f(float z){
    return fmaxf(z, 0.0f) + log1pf(__expf(-fabsf(z)));
}
__device__ __forceinline__ float gelu_f(float x){
    float u = 0.7978845608028654f*(x + 0.044715f*x*x*x);
    float e = __builtin_amdgcn_exp2f(2.0f*LOG2E*u);
    float th = 1.0f - 2.0f*__builtin_amdgcn_rcpf(e + 1.0f);
    return 0.5f*x*(1.0f + th);
}

// Pack weights (fp32 -> f16) into MFMA B-fragment order.
__global__ __launch_bounds__(256) void pack_w_k(const float* __restrict__ Wd,
                         const float* __restrict__ WB,
                         const float* __restrict__ WC,
                         const float* __restrict__ Wm,
                         _Float16* __restrict__ pd0, _Float16* __restrict__ pm0,
                         _Float16* __restrict__ pd1, _Float16* __restrict__ pm1){
    int cfg = blockIdx.y;
    int layer = cfg >> 1;
    int isMix = cfg & 1;
    int count = isMix ? 16*8*64 : 18*8*64;
    int t = blockIdx.x*256 + threadIdx.x;
    if (t >= count) return;
    int lane = t & 63;
    int ks   = (t >> 6) & 7;
    int nt16 = t >> 9;
    int col  = nt16*16 + (lane & 15);
    int kb   = ks*32 + ((lane >> 4) << 3);
    const float* Wd_l = Wd + (size_t)layer*DM*DM;
    const float* WB_l = WB + (size_t)layer*DM*NS;
    const float* WC_l = WC + (size_t)layer*DM*NS;
    const float* Wm_l = Wm + (size_t)layer*DM*DM;
    f16x8 v;
    #pragma unroll
    for (int i=0;i<8;++i){
        float s;
        if (isMix)          s = Wm_l[(size_t)(kb+i)*DM + col];
        else if (col < 256) s = Wd_l[(size_t)(kb+i)*DM + col];
        else if (col < 272) s = WB_l[(size_t)(kb+i)*NS + (col-256)];
        else                s = WC_l[(size_t)(kb+i)*NS + (col-272)];
        v[i] = (_Float16)s;
    }
    _Float16* dst = isMix ? (layer ? pm1 : pm0) : (layer ? pd1 : pd0);
    ((f16x8*)dst)[t] = v;
}

// Fused RMSNorm + dtbc GEMM. Block = 32 rows, 576 threads (9 MFMA waves).
__global__ __launch_bounds__(576) void fused_pre(const float* __restrict__ xin,
                          const _Float16* __restrict__ wp,
                          const float* __restrict__ bd,
                          float* __restrict__ xn,
                          float* __restrict__ dt,
                          float* __restrict__ Bm,
                          float* __restrict__ Cm){
    __shared__ _Float16 xs[32*32*8];   // 16 KB
    int t = threadIdx.x;
    int row0 = blockIdx.x*32;
    if (t < 512){
        int r = t >> 4;
        int cb = t & 15;
        const float4* src = (const float4*)(xin + (size_t)(row0+r)*DM);
        float4 v[4];
        float ss = 0.0f;
        #pragma unroll
        for (int j=0;j<4;++j){
            v[j] = src[cb + 16*j];
            ss += v[j].x*v[j].x + v[j].y*v[j].y + v[j].z*v[j].z + v[j].w*v[j].w;
        }
        ss += __shfl_xor(ss, 1, 64);
        ss += __shfl_xor(ss, 2, 64);
        ss += __shfl_xor(ss, 4, 64);
        ss += __shfl_xor(ss, 8, 64);
        float s = rsqrtf(ss*(1.0f/DM) + 1.1920929e-07f);
        float4* xout = (float4*)(xn + (size_t)(row0+r)*DM);
        #pragma unroll
        for (int j=0;j<4;++j){
            int c4 = cb + 16*j;
            float4 o; o.x=v[j].x*s; o.y=v[j].y*s; o.z=v[j].z*s; o.w=v[j].w*s;
            xout[c4] = o;
            int slot = c4 >> 1;
            int j0   = (c4 & 1)*4;
            f16x4 hv; hv[0]=(_Float16)o.x; hv[1]=(_Float16)o.y;
            hv[2]=(_Float16)o.z; hv[3]=(_Float16)o.w;
            *(f16x4*)&xs[((size_t)r*32 + (slot ^ (r & 7)))*8 + j0] = hv;
        }
    }
    __syncthreads();
    int w    = t >> 6;
    int lane = t & 63;
    const f16x8* wpb = (const f16x8*)wp;
    int rl = lane & 15;
    int kg = lane >> 4;
    f32x4 acc[2][2] = {};
    #pragma unroll
    for (int ks=0; ks<8; ++ks){
        int s0 = kg + ks*4;
        f16x8 a0 = *(const f16x8*)&xs[((size_t)(rl     )*32 + (s0 ^ (rl & 7)))*8];
        f16x8 a1 = *(const f16x8*)&xs[((size_t)(rl + 16)*32 + (s0 ^ (rl & 7)))*8];
        f16x8 b0 = wpb[((w*2    )*8 + ks)*64 + lane];
        f16x8 b1 = wpb[((w*2 + 1)*8 + ks)*64 + lane];
        acc[0][0] = __builtin_amdgcn_mfma_f32_16x16x32_f16(a0,b0,acc[0][0],0,0,0);
        acc[0][1] = __builtin_amdgcn_mfma_f32_16x16x32_f16(a0,b1,acc[0][1],0,0,0);
        acc[1][0] = __builtin_amdgcn_mfma_f32_16x16x32_f16(a1,b0,acc[1][0],0,0,0);
        acc[1][1] = __builtin_amdgcn_mfma_f32_16x16x32_f16(a1,b1,acc[1][1],0,0,0);
    }
    int c0 = w*32 + (lane & 15);
    int rb = row0 + ((lane >> 4) << 2);
    if (w < 8){
        float bias0 = bd[c0], bias1 = bd[c0 + 16];
        #pragma unroll
        for (int mi=0; mi<2; ++mi){
            #pragma unroll
            for (int r=0; r<4; ++r){
                int grow = rb + mi*16 + r;
                dt[(size_t)grow*DM + c0]      = softplus_f(acc[mi][0][r] + bias0);
                dt[(size_t)grow*DM + c0 + 16] = softplus_f(acc[mi][1][r] + bias1);
            }
        }
    } else {
        int n = lane & 15;
        #pragma unroll
        for (int mi=0; mi<2; ++mi){
            #pragma unroll
            for (int r=0; r<4; ++r){
                int grow = rb + mi*16 + r;
                Bm[(size_t)grow*NS + n] = acc[mi][0][r];
                Cm[(size_t)grow*NS + n] = acc[mi][1][r];
            }
        }
    }
}

// Fused mix-GEMM + RMSNorm + next-layer dtbc-GEMM. 576 threads, 32 rows/block.
__global__ __launch_bounds__(576) void fused_mid(const _Float16* __restrict__ yh,
                          const _Float16* __restrict__ wpm,
                          const float* __restrict__ bm,
                          const _Float16* __restrict__ wpd,
                          const float* __restrict__ bd,
                          float* __restrict__ xn,
                          float* __restrict__ dt,
                          float* __restrict__ Bm,
                          float* __restrict__ Cm){
    __shared__ float ms[32*MS_STRIDE];   // 32.5 KB mix output
    __shared__ _Float16 xs[32*32*8];     // 16 KB f16 fragments
    int t = threadIdx.x;
    int w = t >> 6, lane = t & 63;
    int row0 = blockIdx.x*32;
    if (w < 8){
        const f16x8* ah  = (const f16x8*)yh;
        const f16x8* wpb = (const f16x8*)wpm;
        size_t a0i = (size_t)(row0 + (lane & 15))*32 + (lane >> 4);
        f32x4 acc[2][2] = {};
        #pragma unroll
        for (int ks=0; ks<8; ++ks){
            f16x8 a0 = ah[a0i + ks*4];
            f16x8 a1 = ah[a0i + 512 + ks*4];
            f16x8 b0 = wpb[((w*2    )*8 + ks)*64 + lane];
            f16x8 b1 = wpb[((w*2 + 1)*8 + ks)*64 + lane];
            acc[0][0] = __builtin_amdgcn_mfma_f32_16x16x32_f16(a0,b0,acc[0][0],0,0,0);
            acc[0][1] = __builtin_amdgcn_mfma_f32_16x16x32_f16(a0,b1,acc[0][1],0,0,0);
            acc[1][0] = __builtin_amdgcn_mfma_f32_16x16x32_f16(a1,b0,acc[1][0],0,0,0);
            acc[1][1] = __builtin_amdgcn_mfma_f32_16x16x32_f16(a1,b1,acc[1][1],0,0,0);
        }
        int c0 = w*32 + (lane & 15);
        int rb = (lane >> 4) << 2;
        float bias0 = bm[c0], bias1 = bm[c0 + 16];
        #pragma unroll
        for (int mi=0; mi<2; ++mi){
            #pragma unroll
            for (int r=0; r<4; ++r){
                int lr = rb + mi*16 + r;
                ms[lr*MS_STRIDE + c0]      = acc[mi][0][r] + bias0;
                ms[lr*MS_STRIDE + c0 + 16] = acc[mi][1][r] + bias1;
            }
        }
    }
    __syncthreads();
    if (t < 512){
        int r = t >> 4;
        int cb = t & 15;
        float4 v[4];
        float ss = 0.0f;
        #pragma unroll
        for (int j=0;j<4;++j){
            v[j] = *(const float4*)&ms[r*MS_STRIDE + (cb + 16*j)*4];
            ss += v[j].x*v[j].x + v[j].y*v[j].y + v[j].z*v[j].z + v[j].w*v[j].w;
        }
        ss += __shfl_xor(ss, 1, 64);
        ss += __shfl_xor(ss, 2, 64);
        ss += __shfl_xor(ss, 4, 64);
        ss += __shfl_xor(ss, 8, 64);
        float s = rsqrtf(ss*(1.0f/DM) + 1.1920929e-07f);
        float4* xout = (float4*)(xn + (size_t)(row0+r)*DM);
        #pragma unroll
        for (int j=0;j<4;++j){
            int c4 = cb + 16*j;
            float4 o; o.x=v[j].x*s; o.y=v[j].y*s; o.z=v[j].z*s; o.w=v[j].w*s;
            xout[c4] = o;
            int slot = c4 >> 1;
            int j0   = (c4 & 1)*4;
            f16x4 hv; hv[0]=(_Float16)o.x; hv[1]=(_Float16)o.y;
            hv[2]=(_Float16)o.z; hv[3]=(_Float16)o.w;
            *(f16x4*)&xs[((size_t)r*32 + (slot ^ (r & 7)))*8 + j0] = hv;
        }
    }
    __syncthreads();
    {
        const f16x8* wpb = (const f16x8*)wpd;
        int rl = lane & 15;
        int kg = lane >> 4;
        f32x4 acc[2][2] = {};
        #pragma unroll
        for (int ks=0; ks<8; ++ks){
            int s0 = kg + ks*4;
            f16x8 a0 = *(const f16x8*)&xs[((size_t)(rl     )*32 + (s0 ^ (rl & 7)))*8];
            f16x8 a1 = *(const f16x8*)&xs[((size_t)(rl + 16)*32 + (s0 ^ (rl & 7)))*8];
            f16x8 b0 = wpb[((w*2    )*8 + ks)*64 + lane];
            f16x8 b1 = wpb[((w*2 + 1)*8 + ks)*64 + lane];
            acc[0][0] = __builtin_amdgcn_mfma_f32_16x16x32_f16(a0,b0,acc[0][0],0,0,0);
            acc[0][1] = __builtin_amdgcn_mfma_f32_16x16x32_f16(a0,b1,acc[0][1],0,0,0);
            acc[1][0] = __builtin_amdgcn_mfma_f32_16x16x32_f16(a1,b0,acc[1][0],0,0,0);
            acc[1][1] = __builtin_amdgcn_mfma_f32_16x16x32_f16(a1,b1,acc[1][1],0,0,0);
        }
        int c0 = w*32 + (lane & 15);
        int rb = row0 + ((lane >> 4) << 2);
        if (w < 8){
            float bias0 = bd[c0], bias1 = bd[c0 + 16];
            #pragma unroll
            for (int mi=0; mi<2; ++mi){
                #pragma unroll
                for (int r=0; r<4; ++r){
                    int grow = rb + mi*16 + r;
                    dt[(size_t)grow*DM + c0]      = softplus_f(acc[mi][0][r] + bias0);
                    dt[(size_t)grow*DM + c0 + 16] = softplus_f(acc[mi][1][r] + bias1);
                }
            }
        } else {
            int n = lane & 15;
            #pragma unroll
            for (int mi=0; mi<2; ++mi){
                #pragma unroll
                for (int r=0; r<4; ++r){
                    int grow = rb + mi*16 + r;
                    Bm[(size_t)grow*NS + n] = acc[mi][0][r];
                    Cm[(size_t)grow*NS + n] = acc[mi][1][r];
                }
            }
        }
    }
}

// Fused final mix-GEMM + final RMSNorm -> out. 512 threads, 32 rows/block.
__global__ __launch_bounds__(512) void fused_out(const _Float16* __restrict__ yh,
                          const _Float16* __restrict__ wpm,
                          const float* __restrict__ bm,
                          float* __restrict__ out){
    __shared__ float ms[32*MS_STRIDE];
    int t = threadIdx.x;
    int w = t >> 6, lane = t & 63;
    int row0 = blockIdx.x*32;
    {
        const f16x8* ah  = (const f16x8*)yh;
        const f16x8* wpb = (const f16x8*)wpm;
        size_t a0i = (size_t)(row0 + (lane & 15))*32 + (lane >> 4);
        f32x4 acc[2][2] = {};
        #pragma unroll
        for (int ks=0; ks<8; ++ks){
            f16x8 a0 = ah[a0i + ks*4];
            f16x8 a1 = ah[a0i + 512 + ks*4];
            f16x8 b0 = wpb[((w*2    )*8 + ks)*64 + lane];
            f16x8 b1 = wpb[((w*2 + 1)*8 + ks)*64 + lane];
            acc[0][0] = __builtin_amdgcn_mfma_f32_16x16x32_f16(a0,b0,acc[0][0],0,0,0);
            acc[0][1] = __builtin_amdgcn_mfma_f32_16x16x32_f16(a0,b1,acc[0][1],0,0,0);
            acc[1][0] = __builtin_amdgcn_mfma_f32_16x16x32_f16(a1,b0,acc[1][0],0,0,0);
            acc[1][1] = __builtin_amdgcn_mfma_f32_16x16x32_f16(a1,b1,acc[1][1],0,0,0);
        }
        int c0 = w*32 + (lane & 15);
        int rb = (lane >> 4) << 2;
        float bias0 = bm[c0], bias1 = bm[c0 + 16];
        #pragma unroll
        for (int mi=0; mi<2; ++mi){
            #pragma unroll
            for (int r=0; r<4; ++r){
                int lr = rb + mi*16 + r;
                ms[lr*MS_STRIDE + c0]      = acc[mi][0][r] + bias0;
                ms[lr*MS_STRIDE + c0 + 16] = acc[mi][1][r] + bias1;
            }
        }
    }
    __syncthreads();
    {
        int r = t >> 4;
        int cb = t & 15;
        float4 v[4];
        float ss = 0.0f;
        #pragma unroll
        for (int j=0;j<4;++j){
            v[j] = *(const float4*)&ms[r*MS_STRIDE + (cb + 16*j)*4];
            ss += v[j].x*v[j].x + v[j].y*v[j].y + v[j].z*v[j].z + v[j].w*v[j].w;
        }
        ss += __shfl_xor(ss, 1, 64);
        ss += __shfl_xor(ss, 2, 64);
        ss += __shfl_xor(ss, 4, 64);
        ss += __shfl_xor(ss, 8, 64);
        float s = rsqrtf(ss*(1.0f/DM) + 1.1920929e-07f);
        float4* xout = (float4*)(out + (size_t)(row0+r)*DM);
        #pragma unroll
        for (int j=0;j<4;++j){
            float4 o = v[j];
            o.x*=s; o.y*=s; o.z*=s; o.w*=s;
            xout[cb + 16*j] = o;
        }
    }
}

// Scan phase 1: chunk summaries, LDS-staged coalesced dt/xn reads.
// grid (NCHUNK, DM/64, BATCH) x 256; thread = (d, n-quad).
__global__ __launch_bounds__(256) void scan_p1(const float* __restrict__ xn,
                        const float* __restrict__ dt,
                        const float* __restrict__ Bmv,
                        const float* __restrict__ A,
                        float* __restrict__ cA, float* __restrict__ cB){
    __shared__ float sdt[CHUNK][64];
    __shared__ float sxn[CHUNK][64];
    __shared__ float4 bs[CHUNK*4];
    int tid = threadIdx.x;
    int c = blockIdx.x, dq = blockIdx.y, b = blockIdx.z;
    int dl = tid >> 2, nq = tid & 3;
    int d  = dq*64 + dl;
    int row0 = b*LSEQ + c*CHUNK;
    {
        int t0 = tid >> 4, cg = tid & 15;
        *(float4*)&sdt[t0][cg*4] = *(const float4*)(dt + (size_t)(row0+t0)*DM + dq*64 + cg*4);
        *(float4*)&sxn[t0][cg*4] = *(const float4*)(xn + (size_t)(row0+t0)*DM + dq*64 + cg*4);
        int t1 = t0 + 16;
        *(float4*)&sdt[t1][cg*4] = *(const float4*)(dt + (size_t)(row0+t1)*DM + dq*64 + cg*4);
        *(float4*)&sxn[t1][cg*4] = *(const float4*)(xn + (size_t)(row0+t1)*DM + dq*64 + cg*4);
    }
    if (tid < CHUNK*4) bs[tid] = ((const float4*)(Bmv + (size_t)row0*NS))[tid];
    float4 Alg = ((const float4*)(A + (size_t)d*NS))[nq];
    Alg.x *= LOG2E; Alg.y *= LOG2E; Alg.z *= LOG2E; Alg.w *= LOG2E;
    __syncthreads();
    float Ap0=1,Ap1=1,Ap2=1,Ap3=1, Bp0=0,Bp1=0,Bp2=0,Bp3=0;
    #pragma unroll 4
    for (int tt=0; tt<CHUNK; ++tt){
        float dtv = sdt[tt][dl];
        float xv  = sxn[tt][dl];
        float dtx = dtv*xv;
        float4 bq = bs[tt*4 + nq];
        float a0 = __builtin_amdgcn_exp2f(dtv*Alg.x);
        float a1 = __builtin_amdgcn_exp2f(dtv*Alg.y);
        float a2 = __builtin_amdgcn_exp2f(dtv*Alg.z);
        float a3 = __builtin_amdgcn_exp2f(dtv*Alg.w);
        Ap0 *= a0; Bp0 = fmaf(a0, Bp0, dtx*bq.x);
        Ap1 *= a1; Bp1 = fmaf(a1, Bp1, dtx*bq.y);
        Ap2 *= a2; Bp2 = fmaf(a2, Bp2, dtx*bq.z);
        Ap3 *= a3; Bp3 = fmaf(a3, Bp3, dtx*bq.w);
    }
    size_t base = (size_t)c*NCHAIN + ((size_t)b*DM + d)*NS + nq*4;
    *(float4*)(cA + base) = make_float4(Ap0,Ap1,Ap2,Ap3);
    *(float4*)(cB + base) = make_float4(Bp0,Bp1,Bp2,Bp3);
}

// Phase 3 with inline prefix: h_in = forward composition of cA/cB[0..c-1]
// (identical op order to the old scan_p2 -> bitwise-same results, no sync
// needed because cA/cB come from the previous kernel). Then replay + y.
__global__ __launch_bounds__(256) void scan_p3(const float* __restrict__ xn,
                        const float* __restrict__ dt,
                        const float* __restrict__ Bmv,
                        const float* __restrict__ Cmv,
                        const float* __restrict__ A,
                        const float* __restrict__ Dsk,
                        const float* __restrict__ cA,
                        const float* __restrict__ cB,
                        _Float16* __restrict__ yh){
    __shared__ float sdt[CHUNK][64];
    __shared__ float sxn[CHUNK][64];
    __shared__ float4 bs[CHUNK*4], cs[CHUNK*4];
    int tid = threadIdx.x;
    int c = blockIdx.x, dq = blockIdx.y, b = blockIdx.z;
    int dl = tid >> 2, nq = tid & 3;
    int d  = dq*64 + dl;
    int row0 = b*LSEQ + c*CHUNK;
    {
        int t0 = tid >> 4, cg = tid & 15;
        *(float4*)&sdt[t0][cg*4] = *(const float4*)(dt + (size_t)(row0+t0)*DM + dq*64 + cg*4);
        *(float4*)&sxn[t0][cg*4] = *(const float4*)(xn + (size_t)(row0+t0)*DM + dq*64 + cg*4);
        int t1 = t0 + 16;
        *(float4*)&sdt[t1][cg*4] = *(const float4*)(dt + (size_t)(row0+t1)*DM + dq*64 + cg*4);
        *(float4*)&sxn[t1][cg*4] = *(const float4*)(xn + (size_t)(row0+t1)*DM + dq*64 + cg*4);
    }
    if (tid < CHUNK*4){
        bs[tid] = ((const float4*)(Bmv + (size_t)row0*NS))[tid];
        cs[tid] = ((const float4*)(Cmv + (size_t)row0*NS))[tid];
    }
    float4 Alg = ((const float4*)(A + (size_t)d*NS))[nq];
    Alg.x *= LOG2E; Alg.y *= LOG2E; Alg.z *= LOG2E; Alg.w *= LOG2E;
    float dsk = Dsk[d];
    // ---- inline prefix over preceding chunk summaries ----
    float h0=0.0f, h1=0.0f, h2=0.0f, h3=0.0f;
    size_t cbase = ((size_t)b*DM + d)*NS + nq*4;
    #pragma unroll 4
    for (int k=0; k<c; ++k){
        float4 av = *(const float4*)(cA + (size_t)k*NCHAIN + cbase);
        float4 bv = *(const float4*)(cB + (size_t)k*NCHAIN + cbase);
        h0 = fmaf(av.x, h0, bv.x);
        h1 = fmaf(av.y, h1, bv.y);
        h2 = fmaf(av.z, h2, bv.z);
        h3 = fmaf(av.w, h3, bv.w);
    }
    __syncthreads();
    // ---- replay ----
    #pragma unroll 4
    for (int tt=0; tt<CHUNK; ++tt){
        float dtv = sdt[tt][dl];
        float xv  = sxn[tt][dl];
        float dtx = dtv*xv;
        float4 bq = bs[tt*4 + nq];
        float4 cq = cs[tt*4 + nq];
        float a0 = __builtin_amdgcn_exp2f(dtv*Alg.x);
        float a1 = __builtin_amdgcn_exp2f(dtv*Alg.y);
        float a2 = __builtin_amdgcn_exp2f(dtv*Alg.z);
        float a3 = __builtin_amdgcn_exp2f(dtv*Alg.w);
        h0 = fmaf(a0, h0, dtx*bq.x);
        h1 = fmaf(a1, h1, dtx*bq.y);
        h2 = fmaf(a2, h2, dtx*bq.z);
        h3 = fmaf(a3, h3, dtx*bq.w);
        float p = fmaf(h0, cq.x, fmaf(h1, cq.y, fmaf(h2, cq.z, h3*cq.w)));
        p += __shfl_xor(p, 1, 64);
        p += __shfl_xor(p, 2, 64);
        if (nq == 0){
            float yv = p + dsk*xv;
            yh[(size_t)(row0+tt)*DM + d] = (_Float16)gelu_f(yv);
        }
    }
}

extern "C" void kernel_launch(void* const* d_in, const int* in_sizes, int n_in,
                              void* d_out, int out_size, void* d_ws, size_t ws_size,
                              hipStream_t stream) {
    const float* x  = (const float*)d_in[0];
    const float* A  = (const float*)d_in[1];
    const float* Wd = (const float*)d_in[2];
    const float* bd = (const float*)d_in[3];
    const float* WB = (const float*)d_in[4];
    const float* WC = (const float*)d_in[5];
    const float* Ds = (const float*)d_in[6];
    const float* Wm = (const float*)d_in[7];
    const float* bm = (const float*)d_in[8];
    float* out = (float*)d_out;

    const size_t BSZ = (size_t)BL*DM;          // 2,097,152 floats
    const size_t CH  = (size_t)NCHUNK*NCHAIN;  // 1,048,576 floats
    float* ws  = (float*)d_ws;
    float* b0  = ws;                 // xn
    float* b1  = b0  + BSZ;          // dt
    float* Bmb = b1  + BSZ;
    float* Cmb = Bmb + (size_t)BL*NS;
    float* cA  = Cmb + (size_t)BL*NS;
    float* cB  = cA  + CH;
    _Float16* packs = (_Float16*)(cB + CH);
    _Float16* pd0 = packs;
    _Float16* pd1 = pd0 + 73728;
    _Float16* pm0 = pd1 + 73728;
    _Float16* pm1 = pm0 + 65536;
    _Float16* yh  = pm1 + 65536;     // BL*DM f16

    dim3 gscan(NCHUNK, DM/64, BATCH);

    pack_w_k<<<dim3(36,4), 256, 0, stream>>>(Wd, WB, WC, Wm, pd0, pm0, pd1, pm1);

    const float* A1  = A  + (size_t)DM*NS;
    const float* bd1 = bd + DM;
    const float* Ds1 = Ds + DM;
    const float* bm1 = bm + DM;

    // ---- layer 0 ----
    fused_pre<<<BL/32, 576, 0, stream>>>(x, pd0, bd, b0, b1, Bmb, Cmb);
    scan_p1<<<gscan, 256, 0, stream>>>(b0, b1, Bmb, A, cA, cB);
    scan_p3<<<gscan, 256, 0, stream>>>(b0, b1, Bmb, Cmb, A, Ds, cA, cB, yh);
    // ---- mix(L0) + rmsnorm + dtbc(L1) ----
    fused_mid<<<BL/32, 576, 0, stream>>>(yh, pm0, bm, pd1, bd1, b0, b1, Bmb, Cmb);
    // ---- layer 1 scan ----
    scan_p1<<<gscan, 256, 0, stream>>>(b0, b1, Bmb, A1, cA, cB);
    scan_p3<<<gscan, 256, 0, stream>>>(b0, b1, Bmb, Cmb, A1, Ds1, cA, cB, yh);
    // ---- mix(L1) + final rmsnorm ----
    fused_out<<<BL/32, 512, 0, stream>>>(yh, pm1, bm1, out);
}

// Round 9
// 171.168 us; speedup vs baseline: 2.8945x; 1.2910x over previous
//
#include <hip/hip_runtime.h>
#include <hip/hip_bf16.h>

#define BATCH 2
#define LSEQ 4096
#define DM 256
#define NS 16
#define BL (BATCH*LSEQ)
#define CHUNK 32
#define NCHUNK (LSEQ/CHUNK)     // 128
#define NCHAIN (BATCH*DM*NS)    // 8192
#define SEG 8                   // threads per chain in scan_p2
#define CPS (NCHUNK/SEG)        // 16
#define SUM_STRIDE 264          // fp32 LDS row stride for dt/mix buffer
#define LOG2E 1.4426950408889634f

typedef _Float16 f16x8 __attribute__((ext_vector_type(8)));
typedef _Float16 f16x4 __attribute__((ext_vector_type(4)));
typedef float f32x4 __attribute__((ext_vector_type(4)));

__device__ __forceinline__ float softplus_f(float z){
    return fmaxf(z, 0.0f) + log1pf(__expf(-fabsf(z)));
}
__device__ __forceinline__ float gelu_f(float x){
    float u = 0.7978845608028654f*(x + 0.044715f*x*x*x);
    float e = __builtin_amdgcn_exp2f(2.0f*LOG2E*u);
    float th = 1.0f - 2.0f*__builtin_amdgcn_rcpf(e + 1.0f);
    return 0.5f*x*(1.0f + th);
}

// Pack weights (fp32 -> f16) into MFMA B-fragment order.
__global__ __launch_bounds__(256) void pack_w_k(const float* __restrict__ Wd,
                         const float* __restrict__ WB,
                         const float* __restrict__ WC,
                         const float* __restrict__ Wm,
                         _Float16* __restrict__ pd0, _Float16* __restrict__ pm0,
                         _Float16* __restrict__ pd1, _Float16* __restrict__ pm1){
    int cfg = blockIdx.y;
    int layer = cfg >> 1;
    int isMix = cfg & 1;
    int count = isMix ? 16*8*64 : 18*8*64;
    int t = blockIdx.x*256 + threadIdx.x;
    if (t >= count) return;
    int lane = t & 63;
    int ks   = (t >> 6) & 7;
    int nt16 = t >> 9;
    int col  = nt16*16 + (lane & 15);
    int kb   = ks*32 + ((lane >> 4) << 3);
    const float* Wd_l = Wd + (size_t)layer*DM*DM;
    const float* WB_l = WB + (size_t)layer*DM*NS;
    const float* WC_l = WC + (size_t)layer*DM*NS;
    const float* Wm_l = Wm + (size_t)layer*DM*DM;
    f16x8 v;
    #pragma unroll
    for (int i=0;i<8;++i){
        float s;
        if (isMix)          s = Wm_l[(size_t)(kb+i)*DM + col];
        else if (col < 256) s = Wd_l[(size_t)(kb+i)*DM + col];
        else if (col < 272) s = WB_l[(size_t)(kb+i)*NS + (col-256)];
        else                s = WC_l[(size_t)(kb+i)*NS + (col-272)];
        v[i] = (_Float16)s;
    }
    _Float16* dst = isMix ? (layer ? pm1 : pm0) : (layer ? pd1 : pd0);
    ((f16x8*)dst)[t] = v;
}

// Shared device helper: chunk-summary phase. Requires: buf holds dt (fp32,
// stride SUM_STRIDE), xs holds normalized x (f16, swizzled), bsm holds Bm.
// Threads t<512: ng = t>>8, d = t&255 -> 8 n's each.
__device__ __forceinline__ void chunk_summary(const float* buf,
                    const _Float16* xs, const float* bsm,
                    const float* __restrict__ A,
                    float* __restrict__ cA, float* __restrict__ cB,
                    int b, int c, int t){
    if (t >= 512) return;
    int ng = t >> 8;
    int d  = t & 255;
    float Alg[8];
    {
        const float4* ap = (const float4*)(A + (size_t)d*NS + ng*8);
        float4 a0 = ap[0], a1 = ap[1];
        Alg[0]=a0.x*LOG2E; Alg[1]=a0.y*LOG2E; Alg[2]=a0.z*LOG2E; Alg[3]=a0.w*LOG2E;
        Alg[4]=a1.x*LOG2E; Alg[5]=a1.y*LOG2E; Alg[6]=a1.z*LOG2E; Alg[7]=a1.w*LOG2E;
    }
    float Ap[8], Bp[8];
    #pragma unroll
    for (int j=0;j<8;++j){ Ap[j]=1.0f; Bp[j]=0.0f; }
    int xsl = d >> 3, xel = d & 7;
    #pragma unroll 4
    for (int tt=0; tt<CHUNK; ++tt){
        float dtv = buf[tt*SUM_STRIDE + d];
        float xv  = (float)xs[((size_t)tt*32 + (xsl ^ (tt & 7)))*8 + xel];
        float dtx = dtv*xv;
        const float4* bp4 = (const float4*)&bsm[tt*16 + ng*8];
        float4 b0 = bp4[0], b1 = bp4[1];
        float bv[8] = {b0.x,b0.y,b0.z,b0.w,b1.x,b1.y,b1.z,b1.w};
        #pragma unroll
        for (int j=0;j<8;++j){
            float a = __builtin_amdgcn_exp2f(dtv*Alg[j]);
            Ap[j] *= a;
            Bp[j] = fmaf(a, Bp[j], dtx*bv[j]);
        }
    }
    size_t base = (size_t)c*NCHAIN + ((size_t)b*DM + d)*NS + ng*8;
    *(float4*)(cA + base)     = make_float4(Ap[0],Ap[1],Ap[2],Ap[3]);
    *(float4*)(cA + base + 4) = make_float4(Ap[4],Ap[5],Ap[6],Ap[7]);
    *(float4*)(cB + base)     = make_float4(Bp[0],Bp[1],Bp[2],Bp[3]);
    *(float4*)(cB + base + 4) = make_float4(Bp[4],Bp[5],Bp[6],Bp[7]);
}

// Fused RMSNorm + dtbc GEMM + chunk summary. Block = 32 rows (one chunk),
// 576 threads (9 MFMA waves).
__global__ __launch_bounds__(576) void fused_pre_s(const float* __restrict__ xin,
                          const _Float16* __restrict__ wp,
                          const float* __restrict__ bd,
                          const float* __restrict__ A,
                          float* __restrict__ xn,
                          float* __restrict__ dt,
                          float* __restrict__ Bm,
                          float* __restrict__ Cm,
                          float* __restrict__ cA,
                          float* __restrict__ cB){
    __shared__ float buf[32*SUM_STRIDE];   // dt (fp32) for summary
    __shared__ _Float16 xs[32*32*8];       // 16 KB f16 fragments
    __shared__ float bsm[32*16];           // Bm chunk tile
    int t = threadIdx.x;
    int row0 = blockIdx.x*32;
    int b = row0 >> 12;
    int c = (row0 & (LSEQ-1)) >> 5;
    if (t < 512){
        int r = t >> 4;
        int cb = t & 15;
        const float4* src = (const float4*)(xin + (size_t)(row0+r)*DM);
        float4 v[4];
        float ss = 0.0f;
        #pragma unroll
        for (int j=0;j<4;++j){
            v[j] = src[cb + 16*j];
            ss += v[j].x*v[j].x + v[j].y*v[j].y + v[j].z*v[j].z + v[j].w*v[j].w;
        }
        ss += __shfl_xor(ss, 1, 64);
        ss += __shfl_xor(ss, 2, 64);
        ss += __shfl_xor(ss, 4, 64);
        ss += __shfl_xor(ss, 8, 64);
        float s = rsqrtf(ss*(1.0f/DM) + 1.1920929e-07f);
        float4* xout = (float4*)(xn + (size_t)(row0+r)*DM);
        #pragma unroll
        for (int j=0;j<4;++j){
            int c4 = cb + 16*j;
            float4 o; o.x=v[j].x*s; o.y=v[j].y*s; o.z=v[j].z*s; o.w=v[j].w*s;
            xout[c4] = o;
            int slot = c4 >> 1;
            int j0   = (c4 & 1)*4;
            f16x4 hv; hv[0]=(_Float16)o.x; hv[1]=(_Float16)o.y;
            hv[2]=(_Float16)o.z; hv[3]=(_Float16)o.w;
            *(f16x4*)&xs[((size_t)r*32 + (slot ^ (r & 7)))*8 + j0] = hv;
        }
    }
    __syncthreads();
    int w    = t >> 6;
    int lane = t & 63;
    {
        const f16x8* wpb = (const f16x8*)wp;
        int rl = lane & 15;
        int kg = lane >> 4;
        f32x4 acc[2][2] = {};
        #pragma unroll
        for (int ks=0; ks<8; ++ks){
            int s0 = kg + ks*4;
            f16x8 a0 = *(const f16x8*)&xs[((size_t)(rl     )*32 + (s0 ^ (rl & 7)))*8];
            f16x8 a1 = *(const f16x8*)&xs[((size_t)(rl + 16)*32 + (s0 ^ (rl & 7)))*8];
            f16x8 b0 = wpb[((w*2    )*8 + ks)*64 + lane];
            f16x8 b1 = wpb[((w*2 + 1)*8 + ks)*64 + lane];
            acc[0][0] = __builtin_amdgcn_mfma_f32_16x16x32_f16(a0,b0,acc[0][0],0,0,0);
            acc[0][1] = __builtin_amdgcn_mfma_f32_16x16x32_f16(a0,b1,acc[0][1],0,0,0);
            acc[1][0] = __builtin_amdgcn_mfma_f32_16x16x32_f16(a1,b0,acc[1][0],0,0,0);
            acc[1][1] = __builtin_amdgcn_mfma_f32_16x16x32_f16(a1,b1,acc[1][1],0,0,0);
        }
        int c0 = w*32 + (lane & 15);
        int lrb = (lane >> 4) << 2;
        if (w < 8){
            float bias0 = bd[c0], bias1 = bd[c0 + 16];
            #pragma unroll
            for (int mi=0; mi<2; ++mi){
                #pragma unroll
                for (int r=0; r<4; ++r){
                    int lr = lrb + mi*16 + r;
                    int grow = row0 + lr;
                    float v0 = softplus_f(acc[mi][0][r] + bias0);
                    float v1 = softplus_f(acc[mi][1][r] + bias1);
                    dt[(size_t)grow*DM + c0]      = v0;
                    dt[(size_t)grow*DM + c0 + 16] = v1;
                    buf[lr*SUM_STRIDE + c0]      = v0;
                    buf[lr*SUM_STRIDE + c0 + 16] = v1;
                }
            }
        } else {
            int n = lane & 15;
            #pragma unroll
            for (int mi=0; mi<2; ++mi){
                #pragma unroll
                for (int r=0; r<4; ++r){
                    int lr = lrb + mi*16 + r;
                    int grow = row0 + lr;
                    Bm[(size_t)grow*NS + n] = acc[mi][0][r];
                    Cm[(size_t)grow*NS + n] = acc[mi][1][r];
                    bsm[lr*16 + n] = acc[mi][0][r];
                }
            }
        }
    }
    __syncthreads();
    chunk_summary(buf, xs, bsm, A, cA, cB, b, c, t);
}

// Fused mix-GEMM + RMSNorm + next dtbc-GEMM + chunk summary.
// buf is mix-output in phases A/B, then reused for dt in phase C.
__global__ __launch_bounds__(576) void fused_mid_s(const _Float16* __restrict__ yh,
                          const _Float16* __restrict__ wpm,
                          const float* __restrict__ bm,
                          const _Float16* __restrict__ wpd,
                          const float* __restrict__ bd,
                          const float* __restrict__ A,
                          float* __restrict__ xn,
                          float* __restrict__ dt,
                          float* __restrict__ Bm,
                          float* __restrict__ Cm,
                          float* __restrict__ cA,
                          float* __restrict__ cB){
    __shared__ float buf[32*SUM_STRIDE];
    __shared__ _Float16 xs[32*32*8];
    __shared__ float bsm[32*16];
    int t = threadIdx.x;
    int w = t >> 6, lane = t & 63;
    int row0 = blockIdx.x*32;
    int b = row0 >> 12;
    int c = (row0 & (LSEQ-1)) >> 5;
    // ---- phase A: mix GEMM -> buf ----
    if (w < 8){
        const f16x8* ah  = (const f16x8*)yh;
        const f16x8* wpb = (const f16x8*)wpm;
        size_t a0i = (size_t)(row0 + (lane & 15))*32 + (lane >> 4);
        f32x4 acc[2][2] = {};
        #pragma unroll
        for (int ks=0; ks<8; ++ks){
            f16x8 a0 = ah[a0i + ks*4];
            f16x8 a1 = ah[a0i + 512 + ks*4];
            f16x8 b0 = wpb[((w*2    )*8 + ks)*64 + lane];
            f16x8 b1 = wpb[((w*2 + 1)*8 + ks)*64 + lane];
            acc[0][0] = __builtin_amdgcn_mfma_f32_16x16x32_f16(a0,b0,acc[0][0],0,0,0);
            acc[0][1] = __builtin_amdgcn_mfma_f32_16x16x32_f16(a0,b1,acc[0][1],0,0,0);
            acc[1][0] = __builtin_amdgcn_mfma_f32_16x16x32_f16(a1,b0,acc[1][0],0,0,0);
            acc[1][1] = __builtin_amdgcn_mfma_f32_16x16x32_f16(a1,b1,acc[1][1],0,0,0);
        }
        int c0 = w*32 + (lane & 15);
        int lrb = (lane >> 4) << 2;
        float bias0 = bm[c0], bias1 = bm[c0 + 16];
        #pragma unroll
        for (int mi=0; mi<2; ++mi){
            #pragma unroll
            for (int r=0; r<4; ++r){
                int lr = lrb + mi*16 + r;
                buf[lr*SUM_STRIDE + c0]      = acc[mi][0][r] + bias0;
                buf[lr*SUM_STRIDE + c0 + 16] = acc[mi][1][r] + bias1;
            }
        }
    }
    __syncthreads();
    // ---- phase B: RMSNorm from buf -> xn global + xs f16 ----
    if (t < 512){
        int r = t >> 4;
        int cb = t & 15;
        float4 v[4];
        float ss = 0.0f;
        #pragma unroll
        for (int j=0;j<4;++j){
            v[j] = *(const float4*)&buf[r*SUM_STRIDE + (cb + 16*j)*4];
            ss += v[j].x*v[j].x + v[j].y*v[j].y + v[j].z*v[j].z + v[j].w*v[j].w;
        }
        ss += __shfl_xor(ss, 1, 64);
        ss += __shfl_xor(ss, 2, 64);
        ss += __shfl_xor(ss, 4, 64);
        ss += __shfl_xor(ss, 8, 64);
        float s = rsqrtf(ss*(1.0f/DM) + 1.1920929e-07f);
        float4* xout = (float4*)(xn + (size_t)(row0+r)*DM);
        #pragma unroll
        for (int j=0;j<4;++j){
            int c4 = cb + 16*j;
            float4 o; o.x=v[j].x*s; o.y=v[j].y*s; o.z=v[j].z*s; o.w=v[j].w*s;
            xout[c4] = o;
            int slot = c4 >> 1;
            int j0   = (c4 & 1)*4;
            f16x4 hv; hv[0]=(_Float16)o.x; hv[1]=(_Float16)o.y;
            hv[2]=(_Float16)o.z; hv[3]=(_Float16)o.w;
            *(f16x4*)&xs[((size_t)r*32 + (slot ^ (r & 7)))*8 + j0] = hv;
        }
    }
    __syncthreads();
    // ---- phase C: dtbc GEMM; dt -> buf (reuse) + global ----
    {
        const f16x8* wpb = (const f16x8*)wpd;
        int rl = lane & 15;
        int kg = lane >> 4;
        f32x4 acc[2][2] = {};
        #pragma unroll
        for (int ks=0; ks<8; ++ks){
            int s0 = kg + ks*4;
            f16x8 a0 = *(const f16x8*)&xs[((size_t)(rl     )*32 + (s0 ^ (rl & 7)))*8];
            f16x8 a1 = *(const f16x8*)&xs[((size_t)(rl + 16)*32 + (s0 ^ (rl & 7)))*8];
            f16x8 b0 = wpb[((w*2    )*8 + ks)*64 + lane];
            f16x8 b1 = wpb[((w*2 + 1)*8 + ks)*64 + lane];
            acc[0][0] = __builtin_amdgcn_mfma_f32_16x16x32_f16(a0,b0,acc[0][0],0,0,0);
            acc[0][1] = __builtin_amdgcn_mfma_f32_16x16x32_f16(a0,b1,acc[0][1],0,0,0);
            acc[1][0] = __builtin_amdgcn_mfma_f32_16x16x32_f16(a1,b0,acc[1][0],0,0,0);
            acc[1][1] = __builtin_amdgcn_mfma_f32_16x16x32_f16(a1,b1,acc[1][1],0,0,0);
        }
        int c0 = w*32 + (lane & 15);
        int lrb = (lane >> 4) << 2;
        if (w < 8){
            float bias0 = bd[c0], bias1 = bd[c0 + 16];
            #pragma unroll
            for (int mi=0; mi<2; ++mi){
                #pragma unroll
                for (int r=0; r<4; ++r){
                    int lr = lrb + mi*16 + r;
                    int grow = row0 + lr;
                    float v0 = softplus_f(acc[mi][0][r] + bias0);
                    float v1 = softplus_f(acc[mi][1][r] + bias1);
                    dt[(size_t)grow*DM + c0]      = v0;
                    dt[(size_t)grow*DM + c0 + 16] = v1;
                    buf[lr*SUM_STRIDE + c0]      = v0;
                    buf[lr*SUM_STRIDE + c0 + 16] = v1;
                }
            }
        } else {
            int n = lane & 15;
            #pragma unroll
            for (int mi=0; mi<2; ++mi){
                #pragma unroll
                for (int r=0; r<4; ++r){
                    int lr = lrb + mi*16 + r;
                    int grow = row0 + lr;
                    Bm[(size_t)grow*NS + n] = acc[mi][0][r];
                    Cm[(size_t)grow*NS + n] = acc[mi][1][r];
                    bsm[lr*16 + n] = acc[mi][0][r];
                }
            }
        }
    }
    __syncthreads();
    chunk_summary(buf, xs, bsm, A, cA, cB, b, c, t);
}

// Fused final mix-GEMM + final RMSNorm -> out. 512 threads, 32 rows/block.
__global__ __launch_bounds__(512) void fused_out(const _Float16* __restrict__ yh,
                          const _Float16* __restrict__ wpm,
                          const float* __restrict__ bm,
                          float* __restrict__ out){
    __shared__ float ms[32*SUM_STRIDE];
    int t = threadIdx.x;
    int w = t >> 6, lane = t & 63;
    int row0 = blockIdx.x*32;
    {
        const f16x8* ah  = (const f16x8*)yh;
        const f16x8* wpb = (const f16x8*)wpm;
        size_t a0i = (size_t)(row0 + (lane & 15))*32 + (lane >> 4);
        f32x4 acc[2][2] = {};
        #pragma unroll
        for (int ks=0; ks<8; ++ks){
            f16x8 a0 = ah[a0i + ks*4];
            f16x8 a1 = ah[a0i + 512 + ks*4];
            f16x8 b0 = wpb[((w*2    )*8 + ks)*64 + lane];
            f16x8 b1 = wpb[((w*2 + 1)*8 + ks)*64 + lane];
            acc[0][0] = __builtin_amdgcn_mfma_f32_16x16x32_f16(a0,b0,acc[0][0],0,0,0);
            acc[0][1] = __builtin_amdgcn_mfma_f32_16x16x32_f16(a0,b1,acc[0][1],0,0,0);
            acc[1][0] = __builtin_amdgcn_mfma_f32_16x16x32_f16(a1,b0,acc[1][0],0,0,0);
            acc[1][1] = __builtin_amdgcn_mfma_f32_16x16x32_f16(a1,b1,acc[1][1],0,0,0);
        }
        int c0 = w*32 + (lane & 15);
        int lrb = (lane >> 4) << 2;
        float bias0 = bm[c0], bias1 = bm[c0 + 16];
        #pragma unroll
        for (int mi=0; mi<2; ++mi){
            #pragma unroll
            for (int r=0; r<4; ++r){
                int lr = lrb + mi*16 + r;
                ms[lr*SUM_STRIDE + c0]      = acc[mi][0][r] + bias0;
                ms[lr*SUM_STRIDE + c0 + 16] = acc[mi][1][r] + bias1;
            }
        }
    }
    __syncthreads();
    {
        int r = t >> 4;
        int cb = t & 15;
        float4 v[4];
        float ss = 0.0f;
        #pragma unroll
        for (int j=0;j<4;++j){
            v[j] = *(const float4*)&ms[r*SUM_STRIDE + (cb + 16*j)*4];
            ss += v[j].x*v[j].x + v[j].y*v[j].y + v[j].z*v[j].z + v[j].w*v[j].w;
        }
        ss += __shfl_xor(ss, 1, 64);
        ss += __shfl_xor(ss, 2, 64);
        ss += __shfl_xor(ss, 4, 64);
        ss += __shfl_xor(ss, 8, 64);
        float s = rsqrtf(ss*(1.0f/DM) + 1.1920929e-07f);
        float4* xout = (float4*)(out + (size_t)(row0+r)*DM);
        #pragma unroll
        for (int j=0;j<4;++j){
            float4 o = v[j];
            o.x*=s; o.y*=s; o.z*=s; o.w*=s;
            xout[cb + 16*j] = o;
        }
    }
}

// Phase 2: segmented affine scan across chunks. 8 threads/chain.
__global__ __launch_bounds__(256) void scan_p2(const float* __restrict__ cA,
                        const float* __restrict__ cB,
                        float* __restrict__ hin){
    int gt = blockIdx.x*256 + threadIdx.x;
    int chain = gt >> 3;
    int seg   = gt & 7;
    int c0 = seg*CPS;
    float Ac = 1.0f, Bc = 0.0f;
    #pragma unroll 4
    for (int i=0;i<CPS;++i){
        size_t idx = (size_t)(c0+i)*NCHAIN + chain;
        float a = cA[idx], b = cB[idx];
        Bc = fmaf(a, Bc, b);
        Ac *= a;
    }
    #pragma unroll
    for (int dlt=1; dlt<8; dlt<<=1){
        float Apv = __shfl_up(Ac, dlt, 64);
        float Bpv = __shfl_up(Bc, dlt, 64);
        if (seg >= dlt){
            Bc = fmaf(Ac, Bpv, Bc);
            Ac *= Apv;
        }
    }
    float hprev = __shfl_up(Bc, 1, 64);
    float h = (seg == 0) ? 0.0f : hprev;
    #pragma unroll 4
    for (int i=0;i<CPS;++i){
        size_t idx = (size_t)(c0+i)*NCHAIN + chain;
        hin[idx] = h;
        h = fmaf(cA[idx], h, cB[idx]);
    }
}

// Phase 3: replay with h_in; y = sum_n h*C + D_skip*x; emit gelu(y) f16.
// LDS-staged coalesced dt/xn reads.
__global__ __launch_bounds__(256) void scan_p3(const float* __restrict__ xn,
                        const float* __restrict__ dt,
                        const float* __restrict__ Bmv,
                        const float* __restrict__ Cmv,
                        const float* __restrict__ A,
                        const float* __restrict__ Dsk,
                        const float* __restrict__ hin,
                        _Float16* __restrict__ yh){
    __shared__ float sdt[CHUNK][64];
    __shared__ float sxn[CHUNK][64];
    __shared__ float4 bs[CHUNK*4], cs[CHUNK*4];
    int tid = threadIdx.x;
    int c = blockIdx.x, dq = blockIdx.y, b = blockIdx.z;
    int dl = tid >> 2, nq = tid & 3;
    int d  = dq*64 + dl;
    int row0 = b*LSEQ + c*CHUNK;
    {
        int t0 = tid >> 4, cg = tid & 15;
        *(float4*)&sdt[t0][cg*4] = *(const float4*)(dt + (size_t)(row0+t0)*DM + dq*64 + cg*4);
        *(float4*)&sxn[t0][cg*4] = *(const float4*)(xn + (size_t)(row0+t0)*DM + dq*64 + cg*4);
        int t1 = t0 + 16;
        *(float4*)&sdt[t1][cg*4] = *(const float4*)(dt + (size_t)(row0+t1)*DM + dq*64 + cg*4);
        *(float4*)&sxn[t1][cg*4] = *(const float4*)(xn + (size_t)(row0+t1)*DM + dq*64 + cg*4);
    }
    if (tid < CHUNK*4){
        bs[tid] = ((const float4*)(Bmv + (size_t)row0*NS))[tid];
        cs[tid] = ((const float4*)(Cmv + (size_t)row0*NS))[tid];
    }
    float4 Alg = ((const float4*)(A + (size_t)d*NS))[nq];
    Alg.x *= LOG2E; Alg.y *= LOG2E; Alg.z *= LOG2E; Alg.w *= LOG2E;
    float dsk = Dsk[d];
    float4 hv = ((const float4*)(hin + (size_t)c*NCHAIN + ((size_t)b*DM + d)*NS))[nq];
    float h0=hv.x, h1=hv.y, h2=hv.z, h3=hv.w;
    __syncthreads();
    #pragma unroll 4
    for (int tt=0; tt<CHUNK; ++tt){
        float dtv = sdt[tt][dl];
        float xv  = sxn[tt][dl];
        float dtx = dtv*xv;
        float4 bq = bs[tt*4 + nq];
        float4 cq = cs[tt*4 + nq];
        float a0 = __builtin_amdgcn_exp2f(dtv*Alg.x);
        float a1 = __builtin_amdgcn_exp2f(dtv*Alg.y);
        float a2 = __builtin_amdgcn_exp2f(dtv*Alg.z);
        float a3 = __builtin_amdgcn_exp2f(dtv*Alg.w);
        h0 = fmaf(a0, h0, dtx*bq.x);
        h1 = fmaf(a1, h1, dtx*bq.y);
        h2 = fmaf(a2, h2, dtx*bq.z);
        h3 = fmaf(a3, h3, dtx*bq.w);
        float p = fmaf(h0, cq.x, fmaf(h1, cq.y, fmaf(h2, cq.z, h3*cq.w)));
        p += __shfl_xor(p, 1, 64);
        p += __shfl_xor(p, 2, 64);
        if (nq == 0){
            float yv = p + dsk*xv;
            yh[(size_t)(row0+tt)*DM + d] = (_Float16)gelu_f(yv);
        }
    }
}

extern "C" void kernel_launch(void* const* d_in, const int* in_sizes, int n_in,
                              void* d_out, int out_size, void* d_ws, size_t ws_size,
                              hipStream_t stream) {
    const float* x  = (const float*)d_in[0];
    const float* A  = (const float*)d_in[1];
    const float* Wd = (const float*)d_in[2];
    const float* bd = (const float*)d_in[3];
    const float* WB = (const float*)d_in[4];
    const float* WC = (const float*)d_in[5];
    const float* Ds = (const float*)d_in[6];
    const float* Wm = (const float*)d_in[7];
    const float* bm = (const float*)d_in[8];
    float* out = (float*)d_out;

    const size_t BSZ = (size_t)BL*DM;          // 2,097,152 floats
    const size_t CH  = (size_t)NCHUNK*NCHAIN;  // 1,048,576 floats
    float* ws  = (float*)d_ws;
    float* b0  = ws;                 // xn
    float* b1  = b0  + BSZ;          // dt
    float* Bmb = b1  + BSZ;
    float* Cmb = Bmb + (size_t)BL*NS;
    float* cA  = Cmb + (size_t)BL*NS;
    float* cB  = cA  + CH;
    float* hin = cB  + CH;
    _Float16* packs = (_Float16*)(hin + CH);
    _Float16* pd0 = packs;
    _Float16* pd1 = pd0 + 73728;
    _Float16* pm0 = pd1 + 73728;
    _Float16* pm1 = pm0 + 65536;
    _Float16* yh  = pm1 + 65536;     // BL*DM f16

    dim3 gscan(NCHUNK, DM/64, BATCH);

    pack_w_k<<<dim3(36,4), 256, 0, stream>>>(Wd, WB, WC, Wm, pd0, pm0, pd1, pm1);

    const float* A1  = A  + (size_t)DM*NS;
    const float* bd1 = bd + DM;
    const float* Ds1 = Ds + DM;
    const float* bm1 = bm + DM;

    // ---- layer 0 ----
    fused_pre_s<<<BL/32, 576, 0, stream>>>(x, pd0, bd, A, b0, b1, Bmb, Cmb, cA, cB);
    scan_p2<<<NCHAIN*SEG/256, 256, 0, stream>>>(cA, cB, hin);
    scan_p3<<<gscan, 256, 0, stream>>>(b0, b1, Bmb, Cmb, A, Ds, hin, yh);
    // ---- mix(L0) + rmsnorm + dtbc(L1) + summary(L1) ----
    fused_mid_s<<<BL/32, 576, 0, stream>>>(yh, pm0, bm, pd1, bd1, A1,
                                           b0, b1, Bmb, Cmb, cA, cB);
    // ---- layer 1 scan ----
    scan_p2<<<NCHAIN*SEG/256, 256, 0, stream>>>(cA, cB, hin);
    scan_p3<<<gscan, 256, 0, stream>>>(b0, b1, Bmb, Cmb, A1, Ds1, hin, yh);
    // ---- mix(L1) + final rmsnorm ----
    fused_out<<<BL/32, 512, 0, stream>>>(yh, pm1, bm1, out);
}

// Round 10
// 164.750 us; speedup vs baseline: 3.0073x; 1.0390x over previous
//
#include <hip/hip_runtime.h>
#include <hip/hip_bf16.h>

#define BATCH 2
#define LSEQ 4096
#define DM 256
#define NS 16
#define BL (BATCH*LSEQ)
#define CHUNK 32
#define NCHUNK (LSEQ/CHUNK)     // 128
#define NCHAIN (BATCH*DM*NS)    // 8192
#define SEG 8                   // threads per chain in scan_p2
#define CPS (NCHUNK/SEG)        // 16
#define SUM_STRIDE 264          // fp32 LDS row stride
#define LOG2E 1.4426950408889634f

typedef _Float16 f16x8 __attribute__((ext_vector_type(8)));
typedef _Float16 f16x4 __attribute__((ext_vector_type(4)));
typedef float f32x4 __attribute__((ext_vector_type(4)));

__device__ __forceinline__ float softplus_f(float z){
    return fmaxf(z, 0.0f) + log1pf(__expf(-fabsf(z)));
}
__device__ __forceinline__ float gelu_f(float x){
    float u = 0.7978845608028654f*(x + 0.044715f*x*x*x);
    float e = __builtin_amdgcn_exp2f(2.0f*LOG2E*u);
    float th = 1.0f - 2.0f*__builtin_amdgcn_rcpf(e + 1.0f);
    return 0.5f*x*(1.0f + th);
}

// Pack weights (fp32 -> f16) into MFMA B-fragment order.
__global__ __launch_bounds__(256) void pack_w_k(const float* __restrict__ Wd,
                         const float* __restrict__ WB,
                         const float* __restrict__ WC,
                         const float* __restrict__ Wm,
                         _Float16* __restrict__ pd0, _Float16* __restrict__ pm0,
                         _Float16* __restrict__ pd1, _Float16* __restrict__ pm1){
    int cfg = blockIdx.y;
    int layer = cfg >> 1;
    int isMix = cfg & 1;
    int count = isMix ? 16*8*64 : 18*8*64;
    int t = blockIdx.x*256 + threadIdx.x;
    if (t >= count) return;
    int lane = t & 63;
    int ks   = (t >> 6) & 7;
    int nt16 = t >> 9;
    int col  = nt16*16 + (lane & 15);
    int kb   = ks*32 + ((lane >> 4) << 3);
    const float* Wd_l = Wd + (size_t)layer*DM*DM;
    const float* WB_l = WB + (size_t)layer*DM*NS;
    const float* WC_l = WC + (size_t)layer*DM*NS;
    const float* Wm_l = Wm + (size_t)layer*DM*DM;
    f16x8 v;
    #pragma unroll
    for (int i=0;i<8;++i){
        float s;
        if (isMix)          s = Wm_l[(size_t)(kb+i)*DM + col];
        else if (col < 256) s = Wd_l[(size_t)(kb+i)*DM + col];
        else if (col < 272) s = WB_l[(size_t)(kb+i)*NS + (col-256)];
        else                s = WC_l[(size_t)(kb+i)*NS + (col-272)];
        v[i] = (_Float16)s;
    }
    _Float16* dst = isMix ? (layer ? pm1 : pm0) : (layer ? pd1 : pd0);
    ((f16x8*)dst)[t] = v;
}

// chunk-summary helper (512 threads, 8 n's each).
__device__ __forceinline__ void chunk_summary(const float* buf,
                    const _Float16* xs, const float* bsm,
                    const float* __restrict__ A,
                    float* __restrict__ cA, float* __restrict__ cB,
                    int b, int c, int t){
    if (t >= 512) return;
    int ng = t >> 8;
    int d  = t & 255;
    float Alg[8];
    {
        const float4* ap = (const float4*)(A + (size_t)d*NS + ng*8);
        float4 a0 = ap[0], a1 = ap[1];
        Alg[0]=a0.x*LOG2E; Alg[1]=a0.y*LOG2E; Alg[2]=a0.z*LOG2E; Alg[3]=a0.w*LOG2E;
        Alg[4]=a1.x*LOG2E; Alg[5]=a1.y*LOG2E; Alg[6]=a1.z*LOG2E; Alg[7]=a1.w*LOG2E;
    }
    float Ap[8], Bp[8];
    #pragma unroll
    for (int j=0;j<8;++j){ Ap[j]=1.0f; Bp[j]=0.0f; }
    int xsl = d >> 3, xel = d & 7;
    #pragma unroll 4
    for (int tt=0; tt<CHUNK; ++tt){
        float dtv = buf[tt*SUM_STRIDE + d];
        float xv  = (float)xs[((size_t)tt*32 + (xsl ^ (tt & 7)))*8 + xel];
        float dtx = dtv*xv;
        const float4* bp4 = (const float4*)&bsm[tt*16 + ng*8];
        float4 b0 = bp4[0], b1 = bp4[1];
        float bv[8] = {b0.x,b0.y,b0.z,b0.w,b1.x,b1.y,b1.z,b1.w};
        #pragma unroll
        for (int j=0;j<8;++j){
            float a = __builtin_amdgcn_exp2f(dtv*Alg[j]);
            Ap[j] *= a;
            Bp[j] = fmaf(a, Bp[j], dtx*bv[j]);
        }
    }
    size_t base = (size_t)c*NCHAIN + ((size_t)b*DM + d)*NS + ng*8;
    *(float4*)(cA + base)     = make_float4(Ap[0],Ap[1],Ap[2],Ap[3]);
    *(float4*)(cA + base + 4) = make_float4(Ap[4],Ap[5],Ap[6],Ap[7]);
    *(float4*)(cB + base)     = make_float4(Bp[0],Bp[1],Bp[2],Bp[3]);
    *(float4*)(cB + base + 4) = make_float4(Bp[4],Bp[5],Bp[6],Bp[7]);
}

// Fused RMSNorm + dtbc GEMM + chunk summary. Block = 32 rows (one chunk), 576 thr.
__global__ __launch_bounds__(576) void fused_pre_s(const float* __restrict__ xin,
                          const _Float16* __restrict__ wp,
                          const float* __restrict__ bd,
                          const float* __restrict__ A,
                          _Float16* __restrict__ xnh,
                          float* __restrict__ dt,
                          float* __restrict__ Bm,
                          float* __restrict__ Cm,
                          float* __restrict__ cA,
                          float* __restrict__ cB){
    __shared__ float buf[32*SUM_STRIDE];
    __shared__ _Float16 xs[32*32*8];
    __shared__ float bsm[32*16];
    int t = threadIdx.x;
    int row0 = blockIdx.x*32;
    int b = row0 >> 12;
    int c = (row0 & (LSEQ-1)) >> 5;
    if (t < 512){
        int r = t >> 4;
        int cb = t & 15;
        const float4* src = (const float4*)(xin + (size_t)(row0+r)*DM);
        float4 v[4];
        float ss = 0.0f;
        #pragma unroll
        for (int j=0;j<4;++j){
            v[j] = src[cb + 16*j];
            ss += v[j].x*v[j].x + v[j].y*v[j].y + v[j].z*v[j].z + v[j].w*v[j].w;
        }
        ss += __shfl_xor(ss, 1, 64);
        ss += __shfl_xor(ss, 2, 64);
        ss += __shfl_xor(ss, 4, 64);
        ss += __shfl_xor(ss, 8, 64);
        float s = rsqrtf(ss*(1.0f/DM) + 1.1920929e-07f);
        #pragma unroll
        for (int j=0;j<4;++j){
            int c4 = cb + 16*j;
            float4 o; o.x=v[j].x*s; o.y=v[j].y*s; o.z=v[j].z*s; o.w=v[j].w*s;
            int slot = c4 >> 1;
            int j0   = (c4 & 1)*4;
            f16x4 hv; hv[0]=(_Float16)o.x; hv[1]=(_Float16)o.y;
            hv[2]=(_Float16)o.z; hv[3]=(_Float16)o.w;
            *(f16x4*)&xs[((size_t)r*32 + (slot ^ (r & 7)))*8 + j0] = hv;
            *(f16x4*)(xnh + (size_t)(row0+r)*DM + c4*4) = hv;
        }
    }
    __syncthreads();
    int w    = t >> 6;
    int lane = t & 63;
    {
        const f16x8* wpb = (const f16x8*)wp;
        int rl = lane & 15;
        int kg = lane >> 4;
        f32x4 acc[2][2] = {};
        #pragma unroll
        for (int ks=0; ks<8; ++ks){
            int s0 = kg + ks*4;
            f16x8 a0 = *(const f16x8*)&xs[((size_t)(rl     )*32 + (s0 ^ (rl & 7)))*8];
            f16x8 a1 = *(const f16x8*)&xs[((size_t)(rl + 16)*32 + (s0 ^ (rl & 7)))*8];
            f16x8 b0 = wpb[((w*2    )*8 + ks)*64 + lane];
            f16x8 b1 = wpb[((w*2 + 1)*8 + ks)*64 + lane];
            acc[0][0] = __builtin_amdgcn_mfma_f32_16x16x32_f16(a0,b0,acc[0][0],0,0,0);
            acc[0][1] = __builtin_amdgcn_mfma_f32_16x16x32_f16(a0,b1,acc[0][1],0,0,0);
            acc[1][0] = __builtin_amdgcn_mfma_f32_16x16x32_f16(a1,b0,acc[1][0],0,0,0);
            acc[1][1] = __builtin_amdgcn_mfma_f32_16x16x32_f16(a1,b1,acc[1][1],0,0,0);
        }
        int c0 = w*32 + (lane & 15);
        int lrb = (lane >> 4) << 2;
        if (w < 8){
            float bias0 = bd[c0], bias1 = bd[c0 + 16];
            #pragma unroll
            for (int mi=0; mi<2; ++mi){
                #pragma unroll
                for (int r=0; r<4; ++r){
                    int lr = lrb + mi*16 + r;
                    int grow = row0 + lr;
                    float v0 = softplus_f(acc[mi][0][r] + bias0);
                    float v1 = softplus_f(acc[mi][1][r] + bias1);
                    dt[(size_t)grow*DM + c0]      = v0;
                    dt[(size_t)grow*DM + c0 + 16] = v1;
                    buf[lr*SUM_STRIDE + c0]      = v0;
                    buf[lr*SUM_STRIDE + c0 + 16] = v1;
                }
            }
        } else {
            int n = lane & 15;
            #pragma unroll
            for (int mi=0; mi<2; ++mi){
                #pragma unroll
                for (int r=0; r<4; ++r){
                    int lr = lrb + mi*16 + r;
                    int grow = row0 + lr;
                    Bm[(size_t)grow*NS + n] = acc[mi][0][r];
                    Cm[(size_t)grow*NS + n] = acc[mi][1][r];
                    bsm[lr*16 + n] = acc[mi][0][r];
                }
            }
        }
    }
    __syncthreads();
    chunk_summary(buf, xs, bsm, A, cA, cB, b, c, t);
}

// Phase 2: segmented affine scan across chunks. 8 threads/chain.
__global__ __launch_bounds__(256) void scan_p2(const float* __restrict__ cA,
                        const float* __restrict__ cB,
                        float* __restrict__ hin){
    int gt = blockIdx.x*256 + threadIdx.x;
    int chain = gt >> 3;
    int seg   = gt & 7;
    int c0 = seg*CPS;
    float Ac = 1.0f, Bc = 0.0f;
    #pragma unroll 4
    for (int i=0;i<CPS;++i){
        size_t idx = (size_t)(c0+i)*NCHAIN + chain;
        float a = cA[idx], b = cB[idx];
        Bc = fmaf(a, Bc, b);
        Ac *= a;
    }
    #pragma unroll
    for (int dlt=1; dlt<8; dlt<<=1){
        float Apv = __shfl_up(Ac, dlt, 64);
        float Bpv = __shfl_up(Bc, dlt, 64);
        if (seg >= dlt){
            Bc = fmaf(Ac, Bpv, Bc);
            Ac *= Apv;
        }
    }
    float hprev = __shfl_up(Bc, 1, 64);
    float h = (seg == 0) ? 0.0f : hprev;
    #pragma unroll 4
    for (int i=0;i<CPS;++i){
        size_t idx = (size_t)(c0+i)*NCHAIN + chain;
        hin[idx] = h;
        h = fmaf(cA[idx], h, cB[idx]);
    }
}

// Merged: scan replay (layer l) + mix GEMM + RMSNorm + dtbc GEMM (layer l+1)
// + chunk summary (layer l+1). Block = one chunk (32 rows x 256 d), 1024 thr.
__global__ __launch_bounds__(1024) void scan_mid(
                        _Float16* __restrict__ xnh,
                        float* __restrict__ dt,
                        float* __restrict__ Bm,
                        float* __restrict__ Cm,
                        const float* __restrict__ A0,
                        const float* __restrict__ Ds0,
                        const float* __restrict__ hin,
                        const _Float16* __restrict__ wpm,
                        const float* __restrict__ bm,
                        const _Float16* __restrict__ wpd,
                        const float* __restrict__ bd,
                        const float* __restrict__ A1,
                        float* __restrict__ cA,
                        float* __restrict__ cB){
    __shared__ float sdt[32*SUM_STRIDE];      // dt (layer l) -> mix-out -> dt (l+1)
    __shared__ _Float16 sxh[32*32*8];         // x f16 (layer l) -> xs (l+1, swizzled)
    __shared__ _Float16 ys[32*32*8];          // gelu(y) frags (swizzled)
    __shared__ float4 bs4[128], cs4[128];
    __shared__ float bsm[32*16];
    int tid = threadIdx.x;
    int c = blockIdx.x, b = blockIdx.y;
    int row0 = b*LSEQ + c*CHUNK;
    // ---- stage ----
    {
        int r = tid >> 6, c4 = tid & 63;
        *(float4*)&sdt[r*SUM_STRIDE + c4*4] =
            *(const float4*)(dt + (size_t)(row0+r)*DM + c4*4);
        *(float4*)&sdt[(r+16)*SUM_STRIDE + c4*4] =
            *(const float4*)(dt + (size_t)(row0+r+16)*DM + c4*4);
        *(f16x8*)&sxh[(size_t)tid*8] = *(const f16x8*)(xnh + (size_t)row0*DM + (size_t)tid*8);
        if (tid < 128) bs4[tid] = ((const float4*)(Bm + (size_t)row0*NS))[tid];
        else if (tid < 256) cs4[tid-128] = ((const float4*)(Cm + (size_t)row0*NS))[tid-128];
    }
    int dl = tid >> 2, nq = tid & 3;
    float4 Alg = ((const float4*)(A0 + (size_t)dl*NS))[nq];
    Alg.x *= LOG2E; Alg.y *= LOG2E; Alg.z *= LOG2E; Alg.w *= LOG2E;
    float dsk = Ds0[dl];
    float4 hv = *(const float4*)(hin + (size_t)c*NCHAIN + ((size_t)b*DM + dl)*NS + nq*4);
    float h0=hv.x, h1=hv.y, h2=hv.z, h3=hv.w;
    __syncthreads();
    // ---- scan replay; gelu(y) -> ys (frag layout) ----
    #pragma unroll 4
    for (int tt=0; tt<CHUNK; ++tt){
        float dtv = sdt[tt*SUM_STRIDE + dl];
        float xv  = (float)sxh[(size_t)tt*DM + dl];
        float dtx = dtv*xv;
        float4 bq = bs4[tt*4 + nq];
        float4 cq = cs4[tt*4 + nq];
        float a0 = __builtin_amdgcn_exp2f(dtv*Alg.x);
        float a1 = __builtin_amdgcn_exp2f(dtv*Alg.y);
        float a2 = __builtin_amdgcn_exp2f(dtv*Alg.z);
        float a3 = __builtin_amdgcn_exp2f(dtv*Alg.w);
        h0 = fmaf(a0, h0, dtx*bq.x);
        h1 = fmaf(a1, h1, dtx*bq.y);
        h2 = fmaf(a2, h2, dtx*bq.z);
        h3 = fmaf(a3, h3, dtx*bq.w);
        float p = fmaf(h0, cq.x, fmaf(h1, cq.y, fmaf(h2, cq.z, h3*cq.w)));
        p += __shfl_xor(p, 1, 64);
        p += __shfl_xor(p, 2, 64);
        if (nq == 0){
            float yv = p + dsk*xv;
            ys[((size_t)tt*32 + ((dl>>3) ^ (tt & 7)))*8 + (dl & 7)] =
                (_Float16)gelu_f(yv);
        }
    }
    __syncthreads();
    int w = tid >> 6, lane = tid & 63;
    int rl = lane & 15, kg = lane >> 4;
    // ---- mix GEMM (waves 0..7): ys @ wpm -> buf (sdt region) ----
    if (w < 8){
        const f16x8* wpb = (const f16x8*)wpm;
        f32x4 acc[2][2] = {};
        #pragma unroll
        for (int ks=0; ks<8; ++ks){
            int s0 = kg + ks*4;
            f16x8 a0 = *(const f16x8*)&ys[((size_t)(rl     )*32 + (s0 ^ (rl & 7)))*8];
            f16x8 a1 = *(const f16x8*)&ys[((size_t)(rl + 16)*32 + (s0 ^ (rl & 7)))*8];
            f16x8 b0 = wpb[((w*2    )*8 + ks)*64 + lane];
            f16x8 b1 = wpb[((w*2 + 1)*8 + ks)*64 + lane];
            acc[0][0] = __builtin_amdgcn_mfma_f32_16x16x32_f16(a0,b0,acc[0][0],0,0,0);
            acc[0][1] = __builtin_amdgcn_mfma_f32_16x16x32_f16(a0,b1,acc[0][1],0,0,0);
            acc[1][0] = __builtin_amdgcn_mfma_f32_16x16x32_f16(a1,b0,acc[1][0],0,0,0);
            acc[1][1] = __builtin_amdgcn_mfma_f32_16x16x32_f16(a1,b1,acc[1][1],0,0,0);
        }
        int c0 = w*32 + rl;
        int lrb = kg << 2;
        float bias0 = bm[c0], bias1 = bm[c0 + 16];
        #pragma unroll
        for (int mi=0; mi<2; ++mi){
            #pragma unroll
            for (int r=0; r<4; ++r){
                int lr = lrb + mi*16 + r;
                sdt[lr*SUM_STRIDE + c0]      = acc[mi][0][r] + bias0;
                sdt[lr*SUM_STRIDE + c0 + 16] = acc[mi][1][r] + bias1;
            }
        }
    }
    __syncthreads();
    // ---- RMSNorm from buf -> xnh global (f16) + xs (sxh region, swizzled) ----
    if (tid < 512){
        int r = tid >> 4;
        int cb = tid & 15;
        float4 v[4];
        float ss = 0.0f;
        #pragma unroll
        for (int j=0;j<4;++j){
            v[j] = *(const float4*)&sdt[r*SUM_STRIDE + (cb + 16*j)*4];
            ss += v[j].x*v[j].x + v[j].y*v[j].y + v[j].z*v[j].z + v[j].w*v[j].w;
        }
        ss += __shfl_xor(ss, 1, 64);
        ss += __shfl_xor(ss, 2, 64);
        ss += __shfl_xor(ss, 4, 64);
        ss += __shfl_xor(ss, 8, 64);
        float s = rsqrtf(ss*(1.0f/DM) + 1.1920929e-07f);
        #pragma unroll
        for (int j=0;j<4;++j){
            int c4 = cb + 16*j;
            float4 o; o.x=v[j].x*s; o.y=v[j].y*s; o.z=v[j].z*s; o.w=v[j].w*s;
            int slot = c4 >> 1;
            int j0   = (c4 & 1)*4;
            f16x4 hvv; hvv[0]=(_Float16)o.x; hvv[1]=(_Float16)o.y;
            hvv[2]=(_Float16)o.z; hvv[3]=(_Float16)o.w;
            *(f16x4*)&sxh[((size_t)r*32 + (slot ^ (r & 7)))*8 + j0] = hvv;
            *(f16x4*)(xnh + (size_t)(row0+r)*DM + c4*4) = hvv;
        }
    }
    __syncthreads();
    // ---- dtbc GEMM (waves 0..8): xs @ wpd -> dt global + buf, Bm/Cm + bsm ----
    if (w < 9){
        const f16x8* wpb = (const f16x8*)wpd;
        f32x4 acc[2][2] = {};
        #pragma unroll
        for (int ks=0; ks<8; ++ks){
            int s0 = kg + ks*4;
            f16x8 a0 = *(const f16x8*)&sxh[((size_t)(rl     )*32 + (s0 ^ (rl & 7)))*8];
            f16x8 a1 = *(const f16x8*)&sxh[((size_t)(rl + 16)*32 + (s0 ^ (rl & 7)))*8];
            f16x8 b0 = wpb[((w*2    )*8 + ks)*64 + lane];
            f16x8 b1 = wpb[((w*2 + 1)*8 + ks)*64 + lane];
            acc[0][0] = __builtin_amdgcn_mfma_f32_16x16x32_f16(a0,b0,acc[0][0],0,0,0);
            acc[0][1] = __builtin_amdgcn_mfma_f32_16x16x32_f16(a0,b1,acc[0][1],0,0,0);
            acc[1][0] = __builtin_amdgcn_mfma_f32_16x16x32_f16(a1,b0,acc[1][0],0,0,0);
            acc[1][1] = __builtin_amdgcn_mfma_f32_16x16x32_f16(a1,b1,acc[1][1],0,0,0);
        }
        int c0 = w*32 + rl;
        int lrb = kg << 2;
        if (w < 8){
            float bias0 = bd[c0], bias1 = bd[c0 + 16];
            #pragma unroll
            for (int mi=0; mi<2; ++mi){
                #pragma unroll
                for (int r=0; r<4; ++r){
                    int lr = lrb + mi*16 + r;
                    int grow = row0 + lr;
                    float v0 = softplus_f(acc[mi][0][r] + bias0);
                    float v1 = softplus_f(acc[mi][1][r] + bias1);
                    dt[(size_t)grow*DM + c0]      = v0;
                    dt[(size_t)grow*DM + c0 + 16] = v1;
                    sdt[lr*SUM_STRIDE + c0]      = v0;
                    sdt[lr*SUM_STRIDE + c0 + 16] = v1;
                }
            }
        } else {
            int n = rl;
            #pragma unroll
            for (int mi=0; mi<2; ++mi){
                #pragma unroll
                for (int r=0; r<4; ++r){
                    int lr = lrb + mi*16 + r;
                    int grow = row0 + lr;
                    Bm[(size_t)grow*NS + n] = acc[mi][0][r];
                    Cm[(size_t)grow*NS + n] = acc[mi][1][r];
                    bsm[lr*16 + n] = acc[mi][0][r];
                }
            }
        }
    }
    __syncthreads();
    // ---- chunk summary for layer l+1 ----
    chunk_summary(sdt, sxh, bsm, A1, cA, cB, b, c, tid);
}

// Merged: scan replay (layer 1) + mix GEMM + final RMSNorm -> out.
__global__ __launch_bounds__(1024) void scan_out(
                        const _Float16* __restrict__ xnh,
                        const float* __restrict__ dt,
                        const float* __restrict__ Bm,
                        const float* __restrict__ Cm,
                        const float* __restrict__ A1,
                        const float* __restrict__ Ds1,
                        const float* __restrict__ hin,
                        const _Float16* __restrict__ wpm,
                        const float* __restrict__ bm,
                        float* __restrict__ out){
    __shared__ float sdt[32*SUM_STRIDE];
    __shared__ _Float16 sxh[32*32*8];
    __shared__ _Float16 ys[32*32*8];
    __shared__ float4 bs4[128], cs4[128];
    int tid = threadIdx.x;
    int c = blockIdx.x, b = blockIdx.y;
    int row0 = b*LSEQ + c*CHUNK;
    {
        int r = tid >> 6, c4 = tid & 63;
        *(float4*)&sdt[r*SUM_STRIDE + c4*4] =
            *(const float4*)(dt + (size_t)(row0+r)*DM + c4*4);
        *(float4*)&sdt[(r+16)*SUM_STRIDE + c4*4] =
            *(const float4*)(dt + (size_t)(row0+r+16)*DM + c4*4);
        *(f16x8*)&sxh[(size_t)tid*8] = *(const f16x8*)(xnh + (size_t)row0*DM + (size_t)tid*8);
        if (tid < 128) bs4[tid] = ((const float4*)(Bm + (size_t)row0*NS))[tid];
        else if (tid < 256) cs4[tid-128] = ((const float4*)(Cm + (size_t)row0*NS))[tid-128];
    }
    int dl = tid >> 2, nq = tid & 3;
    float4 Alg = ((const float4*)(A1 + (size_t)dl*NS))[nq];
    Alg.x *= LOG2E; Alg.y *= LOG2E; Alg.z *= LOG2E; Alg.w *= LOG2E;
    float dsk = Ds1[dl];
    float4 hv = *(const float4*)(hin + (size_t)c*NCHAIN + ((size_t)b*DM + dl)*NS + nq*4);
    float h0=hv.x, h1=hv.y, h2=hv.z, h3=hv.w;
    __syncthreads();
    #pragma unroll 4
    for (int tt=0; tt<CHUNK; ++tt){
        float dtv = sdt[tt*SUM_STRIDE + dl];
        float xv  = (float)sxh[(size_t)tt*DM + dl];
        float dtx = dtv*xv;
        float4 bq = bs4[tt*4 + nq];
        float4 cq = cs4[tt*4 + nq];
        float a0 = __builtin_amdgcn_exp2f(dtv*Alg.x);
        float a1 = __builtin_amdgcn_exp2f(dtv*Alg.y);
        float a2 = __builtin_amdgcn_exp2f(dtv*Alg.z);
        float a3 = __builtin_amdgcn_exp2f(dtv*Alg.w);
        h0 = fmaf(a0, h0, dtx*bq.x);
        h1 = fmaf(a1, h1, dtx*bq.y);
        h2 = fmaf(a2, h2, dtx*bq.z);
        h3 = fmaf(a3, h3, dtx*bq.w);
        float p = fmaf(h0, cq.x, fmaf(h1, cq.y, fmaf(h2, cq.z, h3*cq.w)));
        p += __shfl_xor(p, 1, 64);
        p += __shfl_xor(p, 2, 64);
        if (nq == 0){
            float yv = p + dsk*xv;
            ys[((size_t)tt*32 + ((dl>>3) ^ (tt & 7)))*8 + (dl & 7)] =
                (_Float16)gelu_f(yv);
        }
    }
    __syncthreads();
    int w = tid >> 6, lane = tid & 63;
    int rl = lane & 15, kg = lane >> 4;
    if (w < 8){
        const f16x8* wpb = (const f16x8*)wpm;
        f32x4 acc[2][2] = {};
        #pragma unroll
        for (int ks=0; ks<8; ++ks){
            int s0 = kg + ks*4;
            f16x8 a0 = *(const f16x8*)&ys[((size_t)(rl     )*32 + (s0 ^ (rl & 7)))*8];
            f16x8 a1 = *(const f16x8*)&ys[((size_t)(rl + 16)*32 + (s0 ^ (rl & 7)))*8];
            f16x8 b0 = wpb[((w*2    )*8 + ks)*64 + lane];
            f16x8 b1 = wpb[((w*2 + 1)*8 + ks)*64 + lane];
            acc[0][0] = __builtin_amdgcn_mfma_f32_16x16x32_f16(a0,b0,acc[0][0],0,0,0);
            acc[0][1] = __builtin_amdgcn_mfma_f32_16x16x32_f16(a0,b1,acc[0][1],0,0,0);
            acc[1][0] = __builtin_amdgcn_mfma_f32_16x16x32_f16(a1,b0,acc[1][0],0,0,0);
            acc[1][1] = __builtin_amdgcn_mfma_f32_16x16x32_f16(a1,b1,acc[1][1],0,0,0);
        }
        int c0 = w*32 + rl;
        int lrb = kg << 2;
        float bias0 = bm[c0], bias1 = bm[c0 + 16];
        #pragma unroll
        for (int mi=0; mi<2; ++mi){
            #pragma unroll
            for (int r=0; r<4; ++r){
                int lr = lrb + mi*16 + r;
                sdt[lr*SUM_STRIDE + c0]      = acc[mi][0][r] + bias0;
                sdt[lr*SUM_STRIDE + c0 + 16] = acc[mi][1][r] + bias1;
            }
        }
    }
    __syncthreads();
    if (tid < 512){
        int r = tid >> 4;
        int cb = tid & 15;
        float4 v[4];
        float ss = 0.0f;
        #pragma unroll
        for (int j=0;j<4;++j){
            v[j] = *(const float4*)&sdt[r*SUM_STRIDE + (cb + 16*j)*4];
            ss += v[j].x*v[j].x + v[j].y*v[j].y + v[j].z*v[j].z + v[j].w*v[j].w;
        }
        ss += __shfl_xor(ss, 1, 64);
        ss += __shfl_xor(ss, 2, 64);
        ss += __shfl_xor(ss, 4, 64);
        ss += __shfl_xor(ss, 8, 64);
        float s = rsqrtf(ss*(1.0f/DM) + 1.1920929e-07f);
        float4* xout = (float4*)(out + (size_t)(row0+r)*DM);
        #pragma unroll
        for (int j=0;j<4;++j){
            float4 o = v[j];
            o.x*=s; o.y*=s; o.z*=s; o.w*=s;
            xout[cb + 16*j] = o;
        }
    }
}

extern "C" void kernel_launch(void* const* d_in, const int* in_sizes, int n_in,
                              void* d_out, int out_size, void* d_ws, size_t ws_size,
                              hipStream_t stream) {
    const float* x  = (const float*)d_in[0];
    const float* A  = (const float*)d_in[1];
    const float* Wd = (const float*)d_in[2];
    const float* bd = (const float*)d_in[3];
    const float* WB = (const float*)d_in[4];
    const float* WC = (const float*)d_in[5];
    const float* Ds = (const float*)d_in[6];
    const float* Wm = (const float*)d_in[7];
    const float* bm = (const float*)d_in[8];
    float* out = (float*)d_out;

    const size_t BSZ = (size_t)BL*DM;          // 2,097,152 elems
    const size_t CH  = (size_t)NCHUNK*NCHAIN;  // 1,048,576 floats
    _Float16* xnh = (_Float16*)d_ws;           // BL*DM f16
    float* dtb = (float*)(xnh + BSZ);          // BL*DM fp32
    float* Bmb = dtb + BSZ;
    float* Cmb = Bmb + (size_t)BL*NS;
    float* cA  = Cmb + (size_t)BL*NS;
    float* cB  = cA  + CH;
    float* hin = cB  + CH;
    _Float16* packs = (_Float16*)(hin + CH);
    _Float16* pd0 = packs;
    _Float16* pd1 = pd0 + 73728;
    _Float16* pm0 = pd1 + 73728;
    _Float16* pm1 = pm0 + 65536;

    pack_w_k<<<dim3(36,4), 256, 0, stream>>>(Wd, WB, WC, Wm, pd0, pm0, pd1, pm1);

    const float* A1  = A  + (size_t)DM*NS;
    const float* bd1 = bd + DM;
    const float* Ds1 = Ds + DM;
    const float* bm1 = bm + DM;

    dim3 gchunk(NCHUNK, BATCH);

    // ---- layer 0: rmsnorm + dtbc GEMM + summaries ----
    fused_pre_s<<<BL/32, 576, 0, stream>>>(x, pd0, bd, A, xnh, dtb, Bmb, Cmb, cA, cB);
    scan_p2<<<NCHAIN*SEG/256, 256, 0, stream>>>(cA, cB, hin);
    // ---- scan(L0) + mix(L0) + rmsnorm + dtbc(L1) + summaries(L1) ----
    scan_mid<<<gchunk, 1024, 0, stream>>>(xnh, dtb, Bmb, Cmb, A, Ds, hin,
                                          pm0, bm, pd1, bd1, A1, cA, cB);
    scan_p2<<<NCHAIN*SEG/256, 256, 0, stream>>>(cA, cB, hin);
    // ---- scan(L1) + mix(L1) + final rmsnorm ----
    scan_out<<<gchunk, 1024, 0, stream>>>(xnh, dtb, Bmb, Cmb, A1, Ds1, hin,
                                          pm1, bm1, out);
}

// Round 11
// 161.137 us; speedup vs baseline: 3.0747x; 1.0224x over previous
//
#include <hip/hip_runtime.h>
#include <hip/hip_bf16.h>

#define BATCH 2
#define LSEQ 4096
#define DM 256
#define NS 16
#define BL (BATCH*LSEQ)
#define CHUNK 32
#define NCHUNK (LSEQ/CHUNK)     // 128
#define NCHAIN (BATCH*DM*NS)    // 8192
#define SEG 8                   // segments per chain in scan_p2
#define CPS (NCHUNK/SEG)        // 16
#define SUM_STRIDE 264          // fp32 LDS row stride
#define LOG2E 1.4426950408889634f

typedef _Float16 f16x8 __attribute__((ext_vector_type(8)));
typedef _Float16 f16x4 __attribute__((ext_vector_type(4)));
typedef float f32x4 __attribute__((ext_vector_type(4)));

__device__ __forceinline__ float softplus_f(float z){
    return fmaxf(z, 0.0f) + log1pf(__expf(-fabsf(z)));
}
__device__ __forceinline__ float gelu_f(float x){
    float u = 0.7978845608028654f*(x + 0.044715f*x*x*x);
    float e = __builtin_amdgcn_exp2f(2.0f*LOG2E*u);
    float th = 1.0f - 2.0f*__builtin_amdgcn_rcpf(e + 1.0f);
    return 0.5f*x*(1.0f + th);
}

// Pack weights (fp32 -> f16) into MFMA B-fragment order.
__global__ __launch_bounds__(256) void pack_w_k(const float* __restrict__ Wd,
                         const float* __restrict__ WB,
                         const float* __restrict__ WC,
                         const float* __restrict__ Wm,
                         _Float16* __restrict__ pd0, _Float16* __restrict__ pm0,
                         _Float16* __restrict__ pd1, _Float16* __restrict__ pm1){
    int cfg = blockIdx.y;
    int layer = cfg >> 1;
    int isMix = cfg & 1;
    int count = isMix ? 16*8*64 : 18*8*64;
    int t = blockIdx.x*256 + threadIdx.x;
    if (t >= count) return;
    int lane = t & 63;
    int ks   = (t >> 6) & 7;
    int nt16 = t >> 9;
    int col  = nt16*16 + (lane & 15);
    int kb   = ks*32 + ((lane >> 4) << 3);
    const float* Wd_l = Wd + (size_t)layer*DM*DM;
    const float* WB_l = WB + (size_t)layer*DM*NS;
    const float* WC_l = WC + (size_t)layer*DM*NS;
    const float* Wm_l = Wm + (size_t)layer*DM*DM;
    f16x8 v;
    #pragma unroll
    for (int i=0;i<8;++i){
        float s;
        if (isMix)          s = Wm_l[(size_t)(kb+i)*DM + col];
        else if (col < 256) s = Wd_l[(size_t)(kb+i)*DM + col];
        else if (col < 272) s = WB_l[(size_t)(kb+i)*NS + (col-256)];
        else                s = WC_l[(size_t)(kb+i)*NS + (col-272)];
        v[i] = (_Float16)s;
    }
    _Float16* dst = isMix ? (layer ? pm1 : pm0) : (layer ? pd1 : pd0);
    ((f16x8*)dst)[t] = v;
}

// chunk-summary helper (512 threads, 8 n's each).
__device__ __forceinline__ void chunk_summary(const float* buf,
                    const _Float16* xs, const float* bsm,
                    const float* __restrict__ A,
                    float* __restrict__ cA, float* __restrict__ cB,
                    int b, int c, int t){
    if (t >= 512) return;
    int ng = t >> 8;
    int d  = t & 255;
    float Alg[8];
    {
        const float4* ap = (const float4*)(A + (size_t)d*NS + ng*8);
        float4 a0 = ap[0], a1 = ap[1];
        Alg[0]=a0.x*LOG2E; Alg[1]=a0.y*LOG2E; Alg[2]=a0.z*LOG2E; Alg[3]=a0.w*LOG2E;
        Alg[4]=a1.x*LOG2E; Alg[5]=a1.y*LOG2E; Alg[6]=a1.z*LOG2E; Alg[7]=a1.w*LOG2E;
    }
    float Ap[8], Bp[8];
    #pragma unroll
    for (int j=0;j<8;++j){ Ap[j]=1.0f; Bp[j]=0.0f; }
    int xsl = d >> 3, xel = d & 7;
    #pragma unroll 4
    for (int tt=0; tt<CHUNK; ++tt){
        float dtv = buf[tt*SUM_STRIDE + d];
        float xv  = (float)xs[((size_t)tt*32 + (xsl ^ (tt & 7)))*8 + xel];
        float dtx = dtv*xv;
        const float4* bp4 = (const float4*)&bsm[tt*16 + ng*8];
        float4 b0 = bp4[0], b1 = bp4[1];
        float bv[8] = {b0.x,b0.y,b0.z,b0.w,b1.x,b1.y,b1.z,b1.w};
        #pragma unroll
        for (int j=0;j<8;++j){
            float a = __builtin_amdgcn_exp2f(dtv*Alg[j]);
            Ap[j] *= a;
            Bp[j] = fmaf(a, Bp[j], dtx*bv[j]);
        }
    }
    size_t base = (size_t)c*NCHAIN + ((size_t)b*DM + d)*NS + ng*8;
    *(float4*)(cA + base)     = make_float4(Ap[0],Ap[1],Ap[2],Ap[3]);
    *(float4*)(cA + base + 4) = make_float4(Ap[4],Ap[5],Ap[6],Ap[7]);
    *(float4*)(cB + base)     = make_float4(Bp[0],Bp[1],Bp[2],Bp[3]);
    *(float4*)(cB + base + 4) = make_float4(Bp[4],Bp[5],Bp[6],Bp[7]);
}

// Fused RMSNorm + dtbc GEMM + chunk summary. Block = 32 rows (one chunk), 576 thr.
__global__ __launch_bounds__(576) void fused_pre_s(const float* __restrict__ xin,
                          const _Float16* __restrict__ wp,
                          const float* __restrict__ bd,
                          const float* __restrict__ A,
                          _Float16* __restrict__ xnh,
                          float* __restrict__ dt,
                          float* __restrict__ Bm,
                          float* __restrict__ Cm,
                          float* __restrict__ cA,
                          float* __restrict__ cB){
    __shared__ float buf[32*SUM_STRIDE];
    __shared__ _Float16 xs[32*32*8];
    __shared__ float bsm[32*16];
    int t = threadIdx.x;
    int row0 = blockIdx.x*32;
    int b = row0 >> 12;
    int c = (row0 & (LSEQ-1)) >> 5;
    if (t < 512){
        int r = t >> 4;
        int cb = t & 15;
        const float4* src = (const float4*)(xin + (size_t)(row0+r)*DM);
        float4 v[4];
        float ss = 0.0f;
        #pragma unroll
        for (int j=0;j<4;++j){
            v[j] = src[cb + 16*j];
            ss += v[j].x*v[j].x + v[j].y*v[j].y + v[j].z*v[j].z + v[j].w*v[j].w;
        }
        ss += __shfl_xor(ss, 1, 64);
        ss += __shfl_xor(ss, 2, 64);
        ss += __shfl_xor(ss, 4, 64);
        ss += __shfl_xor(ss, 8, 64);
        float s = rsqrtf(ss*(1.0f/DM) + 1.1920929e-07f);
        #pragma unroll
        for (int j=0;j<4;++j){
            int c4 = cb + 16*j;
            float4 o; o.x=v[j].x*s; o.y=v[j].y*s; o.z=v[j].z*s; o.w=v[j].w*s;
            int slot = c4 >> 1;
            int j0   = (c4 & 1)*4;
            f16x4 hv; hv[0]=(_Float16)o.x; hv[1]=(_Float16)o.y;
            hv[2]=(_Float16)o.z; hv[3]=(_Float16)o.w;
            *(f16x4*)&xs[((size_t)r*32 + (slot ^ (r & 7)))*8 + j0] = hv;
            *(f16x4*)(xnh + (size_t)(row0+r)*DM + c4*4) = hv;
        }
    }
    __syncthreads();
    int w    = t >> 6;
    int lane = t & 63;
    {
        const f16x8* wpb = (const f16x8*)wp;
        int rl = lane & 15;
        int kg = lane >> 4;
        f32x4 acc[2][2] = {};
        #pragma unroll
        for (int ks=0; ks<8; ++ks){
            int s0 = kg + ks*4;
            f16x8 a0 = *(const f16x8*)&xs[((size_t)(rl     )*32 + (s0 ^ (rl & 7)))*8];
            f16x8 a1 = *(const f16x8*)&xs[((size_t)(rl + 16)*32 + (s0 ^ (rl & 7)))*8];
            f16x8 b0 = wpb[((w*2    )*8 + ks)*64 + lane];
            f16x8 b1 = wpb[((w*2 + 1)*8 + ks)*64 + lane];
            acc[0][0] = __builtin_amdgcn_mfma_f32_16x16x32_f16(a0,b0,acc[0][0],0,0,0);
            acc[0][1] = __builtin_amdgcn_mfma_f32_16x16x32_f16(a0,b1,acc[0][1],0,0,0);
            acc[1][0] = __builtin_amdgcn_mfma_f32_16x16x32_f16(a1,b0,acc[1][0],0,0,0);
            acc[1][1] = __builtin_amdgcn_mfma_f32_16x16x32_f16(a1,b1,acc[1][1],0,0,0);
        }
        int c0 = w*32 + (lane & 15);
        int lrb = (lane >> 4) << 2;
        if (w < 8){
            float bias0 = bd[c0], bias1 = bd[c0 + 16];
            #pragma unroll
            for (int mi=0; mi<2; ++mi){
                #pragma unroll
                for (int r=0; r<4; ++r){
                    int lr = lrb + mi*16 + r;
                    int grow = row0 + lr;
                    float v0 = softplus_f(acc[mi][0][r] + bias0);
                    float v1 = softplus_f(acc[mi][1][r] + bias1);
                    dt[(size_t)grow*DM + c0]      = v0;
                    dt[(size_t)grow*DM + c0 + 16] = v1;
                    buf[lr*SUM_STRIDE + c0]      = v0;
                    buf[lr*SUM_STRIDE + c0 + 16] = v1;
                }
            }
        } else {
            int n = lane & 15;
            #pragma unroll
            for (int mi=0; mi<2; ++mi){
                #pragma unroll
                for (int r=0; r<4; ++r){
                    int lr = lrb + mi*16 + r;
                    int grow = row0 + lr;
                    Bm[(size_t)grow*NS + n] = acc[mi][0][r];
                    Cm[(size_t)grow*NS + n] = acc[mi][1][r];
                    bsm[lr*16 + n] = acc[mi][0][r];
                }
            }
        }
    }
    __syncthreads();
    chunk_summary(buf, xs, bsm, A, cA, cB, b, c, t);
}

// Phase 2: segmented affine scan, chain-quad lanes for coalescing.
// Thread = (chain-quad, seg); wave = 8 quads x 8 segs; lane = seg*8 + qi.
// Per-chain op order identical to previous version (bitwise-same results).
__global__ __launch_bounds__(256) void scan_p2(const float* __restrict__ cA,
                        const float* __restrict__ cB,
                        float* __restrict__ hin){
    int tid  = threadIdx.x;
    int wid  = tid >> 6;
    int lane = tid & 63;
    int seg  = lane >> 3;
    int qi   = lane & 7;
    int quad = (blockIdx.x*4 + wid)*8 + qi;   // 0..NCHAIN/4-1
    const float4* cA4 = (const float4*)cA;
    const float4* cB4 = (const float4*)cB;
    float4* hin4 = (float4*)hin;
    const int NQ = NCHAIN/4;
    int c0 = seg*CPS;
    float Ax=1.0f, Ay=1.0f, Az=1.0f, Aw=1.0f;
    float Bx=0.0f, By=0.0f, Bz=0.0f, Bw=0.0f;
    #pragma unroll 4
    for (int i=0;i<CPS;++i){
        size_t idx = (size_t)(c0+i)*NQ + quad;
        float4 a = cA4[idx];
        float4 b = cB4[idx];
        Bx = fmaf(a.x, Bx, b.x); Ax *= a.x;
        By = fmaf(a.y, By, b.y); Ay *= a.y;
        Bz = fmaf(a.z, Bz, b.z); Az *= a.z;
        Bw = fmaf(a.w, Bw, b.w); Aw *= a.w;
    }
    #pragma unroll
    for (int dlt=1; dlt<8; dlt<<=1){
        float Apx = __shfl_up(Ax, dlt*8, 64), Bpx = __shfl_up(Bx, dlt*8, 64);
        float Apy = __shfl_up(Ay, dlt*8, 64), Bpy = __shfl_up(By, dlt*8, 64);
        float Apz = __shfl_up(Az, dlt*8, 64), Bpz = __shfl_up(Bz, dlt*8, 64);
        float Apw = __shfl_up(Aw, dlt*8, 64), Bpw = __shfl_up(Bw, dlt*8, 64);
        if (seg >= dlt){
            Bx = fmaf(Ax, Bpx, Bx); Ax *= Apx;
            By = fmaf(Ay, Bpy, By); Ay *= Apy;
            Bz = fmaf(Az, Bpz, Bz); Az *= Apz;
            Bw = fmaf(Aw, Bpw, Bw); Aw *= Apw;
        }
    }
    float hx = __shfl_up(Bx, 8, 64);
    float hy = __shfl_up(By, 8, 64);
    float hz = __shfl_up(Bz, 8, 64);
    float hw = __shfl_up(Bw, 8, 64);
    if (seg == 0){ hx = 0.0f; hy = 0.0f; hz = 0.0f; hw = 0.0f; }
    #pragma unroll 4
    for (int i=0;i<CPS;++i){
        size_t idx = (size_t)(c0+i)*NQ + quad;
        hin4[idx] = make_float4(hx, hy, hz, hw);
        float4 a = cA4[idx];
        float4 b = cB4[idx];
        hx = fmaf(a.x, hx, b.x);
        hy = fmaf(a.y, hy, b.y);
        hz = fmaf(a.z, hz, b.z);
        hw = fmaf(a.w, hw, b.w);
    }
}

// Merged: scan replay (layer l) + mix GEMM + RMSNorm + dtbc GEMM (layer l+1)
// + chunk summary (layer l+1). Block = one chunk (32 rows x 256 d), 1024 thr.
__global__ __launch_bounds__(1024) void scan_mid(
                        _Float16* __restrict__ xnh,
                        float* __restrict__ dt,
                        float* __restrict__ Bm,
                        float* __restrict__ Cm,
                        const float* __restrict__ A0,
                        const float* __restrict__ Ds0,
                        const float* __restrict__ hin,
                        const _Float16* __restrict__ wpm,
                        const float* __restrict__ bm,
                        const _Float16* __restrict__ wpd,
                        const float* __restrict__ bd,
                        const float* __restrict__ A1,
                        float* __restrict__ cA,
                        float* __restrict__ cB){
    __shared__ float sdt[32*SUM_STRIDE];      // dt (layer l) -> mix-out -> dt (l+1)
    __shared__ _Float16 sxh[32*32*8];         // x f16 (layer l) -> xs (l+1, swizzled)
    __shared__ _Float16 ys[32*32*8];          // gelu(y) frags (swizzled)
    __shared__ float4 bs4[128], cs4[128];
    __shared__ float bsm[32*16];
    int tid = threadIdx.x;
    int c = blockIdx.x, b = blockIdx.y;
    int row0 = b*LSEQ + c*CHUNK;
    {
        int r = tid >> 6, c4 = tid & 63;
        *(float4*)&sdt[r*SUM_STRIDE + c4*4] =
            *(const float4*)(dt + (size_t)(row0+r)*DM + c4*4);
        *(float4*)&sdt[(r+16)*SUM_STRIDE + c4*4] =
            *(const float4*)(dt + (size_t)(row0+r+16)*DM + c4*4);
        *(f16x8*)&sxh[(size_t)tid*8] = *(const f16x8*)(xnh + (size_t)row0*DM + (size_t)tid*8);
        if (tid < 128) bs4[tid] = ((const float4*)(Bm + (size_t)row0*NS))[tid];
        else if (tid < 256) cs4[tid-128] = ((const float4*)(Cm + (size_t)row0*NS))[tid-128];
    }
    int dl = tid >> 2, nq = tid & 3;
    float4 Alg = ((const float4*)(A0 + (size_t)dl*NS))[nq];
    Alg.x *= LOG2E; Alg.y *= LOG2E; Alg.z *= LOG2E; Alg.w *= LOG2E;
    float dsk = Ds0[dl];
    float4 hv = *(const float4*)(hin + (size_t)c*NCHAIN + ((size_t)b*DM + dl)*NS + nq*4);
    float h0=hv.x, h1=hv.y, h2=hv.z, h3=hv.w;
    __syncthreads();
    #pragma unroll 4
    for (int tt=0; tt<CHUNK; ++tt){
        float dtv = sdt[tt*SUM_STRIDE + dl];
        float xv  = (float)sxh[(size_t)tt*DM + dl];
        float dtx = dtv*xv;
        float4 bq = bs4[tt*4 + nq];
        float4 cq = cs4[tt*4 + nq];
        float a0 = __builtin_amdgcn_exp2f(dtv*Alg.x);
        float a1 = __builtin_amdgcn_exp2f(dtv*Alg.y);
        float a2 = __builtin_amdgcn_exp2f(dtv*Alg.z);
        float a3 = __builtin_amdgcn_exp2f(dtv*Alg.w);
        h0 = fmaf(a0, h0, dtx*bq.x);
        h1 = fmaf(a1, h1, dtx*bq.y);
        h2 = fmaf(a2, h2, dtx*bq.z);
        h3 = fmaf(a3, h3, dtx*bq.w);
        float p = fmaf(h0, cq.x, fmaf(h1, cq.y, fmaf(h2, cq.z, h3*cq.w)));
        p += __shfl_xor(p, 1, 64);
        p += __shfl_xor(p, 2, 64);
        if (nq == 0){
            float yv = p + dsk*xv;
            ys[((size_t)tt*32 + ((dl>>3) ^ (tt & 7)))*8 + (dl & 7)] =
                (_Float16)gelu_f(yv);
        }
    }
    __syncthreads();
    int w = tid >> 6, lane = tid & 63;
    int rl = lane & 15, kg = lane >> 4;
    if (w < 8){
        const f16x8* wpb = (const f16x8*)wpm;
        f32x4 acc[2][2] = {};
        #pragma unroll
        for (int ks=0; ks<8; ++ks){
            int s0 = kg + ks*4;
            f16x8 a0 = *(const f16x8*)&ys[((size_t)(rl     )*32 + (s0 ^ (rl & 7)))*8];
            f16x8 a1 = *(const f16x8*)&ys[((size_t)(rl + 16)*32 + (s0 ^ (rl & 7)))*8];
            f16x8 b0 = wpb[((w*2    )*8 + ks)*64 + lane];
            f16x8 b1 = wpb[((w*2 + 1)*8 + ks)*64 + lane];
            acc[0][0] = __builtin_amdgcn_mfma_f32_16x16x32_f16(a0,b0,acc[0][0],0,0,0);
            acc[0][1] = __builtin_amdgcn_mfma_f32_16x16x32_f16(a0,b1,acc[0][1],0,0,0);
            acc[1][0] = __builtin_amdgcn_mfma_f32_16x16x32_f16(a1,b0,acc[1][0],0,0,0);
            acc[1][1] = __builtin_amdgcn_mfma_f32_16x16x32_f16(a1,b1,acc[1][1],0,0,0);
        }
        int c0 = w*32 + rl;
        int lrb = kg << 2;
        float bias0 = bm[c0], bias1 = bm[c0 + 16];
        #pragma unroll
        for (int mi=0; mi<2; ++mi){
            #pragma unroll
            for (int r=0; r<4; ++r){
                int lr = lrb + mi*16 + r;
                sdt[lr*SUM_STRIDE + c0]      = acc[mi][0][r] + bias0;
                sdt[lr*SUM_STRIDE + c0 + 16] = acc[mi][1][r] + bias1;
            }
        }
    }
    __syncthreads();
    if (tid < 512){
        int r = tid >> 4;
        int cb = tid & 15;
        float4 v[4];
        float ss = 0.0f;
        #pragma unroll
        for (int j=0;j<4;++j){
            v[j] = *(const float4*)&sdt[r*SUM_STRIDE + (cb + 16*j)*4];
            ss += v[j].x*v[j].x + v[j].y*v[j].y + v[j].z*v[j].z + v[j].w*v[j].w;
        }
        ss += __shfl_xor(ss, 1, 64);
        ss += __shfl_xor(ss, 2, 64);
        ss += __shfl_xor(ss, 4, 64);
        ss += __shfl_xor(ss, 8, 64);
        float s = rsqrtf(ss*(1.0f/DM) + 1.1920929e-07f);
        #pragma unroll
        for (int j=0;j<4;++j){
            int c4 = cb + 16*j;
            float4 o; o.x=v[j].x*s; o.y=v[j].y*s; o.z=v[j].z*s; o.w=v[j].w*s;
            int slot = c4 >> 1;
            int j0   = (c4 & 1)*4;
            f16x4 hvv; hvv[0]=(_Float16)o.x; hvv[1]=(_Float16)o.y;
            hvv[2]=(_Float16)o.z; hvv[3]=(_Float16)o.w;
            *(f16x4*)&sxh[((size_t)r*32 + (slot ^ (r & 7)))*8 + j0] = hvv;
            *(f16x4*)(xnh + (size_t)(row0+r)*DM + c4*4) = hvv;
        }
    }
    __syncthreads();
    if (w < 9){
        const f16x8* wpb = (const f16x8*)wpd;
        f32x4 acc[2][2] = {};
        #pragma unroll
        for (int ks=0; ks<8; ++ks){
            int s0 = kg + ks*4;
            f16x8 a0 = *(const f16x8*)&sxh[((size_t)(rl     )*32 + (s0 ^ (rl & 7)))*8];
            f16x8 a1 = *(const f16x8*)&sxh[((size_t)(rl + 16)*32 + (s0 ^ (rl & 7)))*8];
            f16x8 b0 = wpb[((w*2    )*8 + ks)*64 + lane];
            f16x8 b1 = wpb[((w*2 + 1)*8 + ks)*64 + lane];
            acc[0][0] = __builtin_amdgcn_mfma_f32_16x16x32_f16(a0,b0,acc[0][0],0,0,0);
            acc[0][1] = __builtin_amdgcn_mfma_f32_16x16x32_f16(a0,b1,acc[0][1],0,0,0);
            acc[1][0] = __builtin_amdgcn_mfma_f32_16x16x32_f16(a1,b0,acc[1][0],0,0,0);
            acc[1][1] = __builtin_amdgcn_mfma_f32_16x16x32_f16(a1,b1,acc[1][1],0,0,0);
        }
        int c0 = w*32 + rl;
        int lrb = kg << 2;
        if (w < 8){
            float bias0 = bd[c0], bias1 = bd[c0 + 16];
            #pragma unroll
            for (int mi=0; mi<2; ++mi){
                #pragma unroll
                for (int r=0; r<4; ++r){
                    int lr = lrb + mi*16 + r;
                    int grow = row0 + lr;
                    float v0 = softplus_f(acc[mi][0][r] + bias0);
                    float v1 = softplus_f(acc[mi][1][r] + bias1);
                    dt[(size_t)grow*DM + c0]      = v0;
                    dt[(size_t)grow*DM + c0 + 16] = v1;
                    sdt[lr*SUM_STRIDE + c0]      = v0;
                    sdt[lr*SUM_STRIDE + c0 + 16] = v1;
                }
            }
        } else {
            int n = rl;
            #pragma unroll
            for (int mi=0; mi<2; ++mi){
                #pragma unroll
                for (int r=0; r<4; ++r){
                    int lr = lrb + mi*16 + r;
                    int grow = row0 + lr;
                    Bm[(size_t)grow*NS + n] = acc[mi][0][r];
                    Cm[(size_t)grow*NS + n] = acc[mi][1][r];
                    bsm[lr*16 + n] = acc[mi][0][r];
                }
            }
        }
    }
    __syncthreads();
    chunk_summary(sdt, sxh, bsm, A1, cA, cB, b, c, tid);
}

// Merged: scan replay (layer 1) + mix GEMM + final RMSNorm -> out.
__global__ __launch_bounds__(1024) void scan_out(
                        const _Float16* __restrict__ xnh,
                        const float* __restrict__ dt,
                        const float* __restrict__ Bm,
                        const float* __restrict__ Cm,
                        const float* __restrict__ A1,
                        const float* __restrict__ Ds1,
                        const float* __restrict__ hin,
                        const _Float16* __restrict__ wpm,
                        const float* __restrict__ bm,
                        float* __restrict__ out){
    __shared__ float sdt[32*SUM_STRIDE];
    __shared__ _Float16 sxh[32*32*8];
    __shared__ _Float16 ys[32*32*8];
    __shared__ float4 bs4[128], cs4[128];
    int tid = threadIdx.x;
    int c = blockIdx.x, b = blockIdx.y;
    int row0 = b*LSEQ + c*CHUNK;
    {
        int r = tid >> 6, c4 = tid & 63;
        *(float4*)&sdt[r*SUM_STRIDE + c4*4] =
            *(const float4*)(dt + (size_t)(row0+r)*DM + c4*4);
        *(float4*)&sdt[(r+16)*SUM_STRIDE + c4*4] =
            *(const float4*)(dt + (size_t)(row0+r+16)*DM + c4*4);
        *(f16x8*)&sxh[(size_t)tid*8] = *(const f16x8*)(xnh + (size_t)row0*DM + (size_t)tid*8);
        if (tid < 128) bs4[tid] = ((const float4*)(Bm + (size_t)row0*NS))[tid];
        else if (tid < 256) cs4[tid-128] = ((const float4*)(Cm + (size_t)row0*NS))[tid-128];
    }
    int dl = tid >> 2, nq = tid & 3;
    float4 Alg = ((const float4*)(A1 + (size_t)dl*NS))[nq];
    Alg.x *= LOG2E; Alg.y *= LOG2E; Alg.z *= LOG2E; Alg.w *= LOG2E;
    float dsk = Ds1[dl];
    float4 hv = *(const float4*)(hin + (size_t)c*NCHAIN + ((size_t)b*DM + dl)*NS + nq*4);
    float h0=hv.x, h1=hv.y, h2=hv.z, h3=hv.w;
    __syncthreads();
    #pragma unroll 4
    for (int tt=0; tt<CHUNK; ++tt){
        float dtv = sdt[tt*SUM_STRIDE + dl];
        float xv  = (float)sxh[(size_t)tt*DM + dl];
        float dtx = dtv*xv;
        float4 bq = bs4[tt*4 + nq];
        float4 cq = cs4[tt*4 + nq];
        float a0 = __builtin_amdgcn_exp2f(dtv*Alg.x);
        float a1 = __builtin_amdgcn_exp2f(dtv*Alg.y);
        float a2 = __builtin_amdgcn_exp2f(dtv*Alg.z);
        float a3 = __builtin_amdgcn_exp2f(dtv*Alg.w);
        h0 = fmaf(a0, h0, dtx*bq.x);
        h1 = fmaf(a1, h1, dtx*bq.y);
        h2 = fmaf(a2, h2, dtx*bq.z);
        h3 = fmaf(a3, h3, dtx*bq.w);
        float p = fmaf(h0, cq.x, fmaf(h1, cq.y, fmaf(h2, cq.z, h3*cq.w)));
        p += __shfl_xor(p, 1, 64);
        p += __shfl_xor(p, 2, 64);
        if (nq == 0){
            float yv = p + dsk*xv;
            ys[((size_t)tt*32 + ((dl>>3) ^ (tt & 7)))*8 + (dl & 7)] =
                (_Float16)gelu_f(yv);
        }
    }
    __syncthreads();
    int w = tid >> 6, lane = tid & 63;
    int rl = lane & 15, kg = lane >> 4;
    if (w < 8){
        const f16x8* wpb = (const f16x8*)wpm;
        f32x4 acc[2][2] = {};
        #pragma unroll
        for (int ks=0; ks<8; ++ks){
            int s0 = kg + ks*4;
            f16x8 a0 = *(const f16x8*)&ys[((size_t)(rl     )*32 + (s0 ^ (rl & 7)))*8];
            f16x8 a1 = *(const f16x8*)&ys[((size_t)(rl + 16)*32 + (s0 ^ (rl & 7)))*8];
            f16x8 b0 = wpb[((w*2    )*8 + ks)*64 + lane];
            f16x8 b1 = wpb[((w*2 + 1)*8 + ks)*64 + lane];
            acc[0][0] = __builtin_amdgcn_mfma_f32_16x16x32_f16(a0,b0,acc[0][0],0,0,0);
            acc[0][1] = __builtin_amdgcn_mfma_f32_16x16x32_f16(a0,b1,acc[0][1],0,0,0);
            acc[1][0] = __builtin_amdgcn_mfma_f32_16x16x32_f16(a1,b0,acc[1][0],0,0,0);
            acc[1][1] = __builtin_amdgcn_mfma_f32_16x16x32_f16(a1,b1,acc[1][1],0,0,0);
        }
        int c0 = w*32 + rl;
        int lrb = kg << 2;
        float bias0 = bm[c0], bias1 = bm[c0 + 16];
        #pragma unroll
        for (int mi=0; mi<2; ++mi){
            #pragma unroll
            for (int r=0; r<4; ++r){
                int lr = lrb + mi*16 + r;
                sdt[lr*SUM_STRIDE + c0]      = acc[mi][0][r] + bias0;
                sdt[lr*SUM_STRIDE + c0 + 16] = acc[mi][1][r] + bias1;
            }
        }
    }
    __syncthreads();
    if (tid < 512){
        int r = tid >> 4;
        int cb = tid & 15;
        float4 v[4];
        float ss = 0.0f;
        #pragma unroll
        for (int j=0;j<4;++j){
            v[j] = *(const float4*)&sdt[r*SUM_STRIDE + (cb + 16*j)*4];
            ss += v[j].x*v[j].x + v[j].y*v[j].y + v[j].z*v[j].z + v[j].w*v[j].w;
        }
        ss += __shfl_xor(ss, 1, 64);
        ss += __shfl_xor(ss, 2, 64);
        ss += __shfl_xor(ss, 4, 64);
        ss += __shfl_xor(ss, 8, 64);
        float s = rsqrtf(ss*(1.0f/DM) + 1.1920929e-07f);
        float4* xout = (float4*)(out + (size_t)(row0+r)*DM);
        #pragma unroll
        for (int j=0;j<4;++j){
            float4 o = v[j];
            o.x*=s; o.y*=s; o.z*=s; o.w*=s;
            xout[cb + 16*j] = o;
        }
    }
}

extern "C" void kernel_launch(void* const* d_in, const int* in_sizes, int n_in,
                              void* d_out, int out_size, void* d_ws, size_t ws_size,
                              hipStream_t stream) {
    const float* x  = (const float*)d_in[0];
    const float* A  = (const float*)d_in[1];
    const float* Wd = (const float*)d_in[2];
    const float* bd = (const float*)d_in[3];
    const float* WB = (const float*)d_in[4];
    const float* WC = (const float*)d_in[5];
    const float* Ds = (const float*)d_in[6];
    const float* Wm = (const float*)d_in[7];
    const float* bm = (const float*)d_in[8];
    float* out = (float*)d_out;

    const size_t BSZ = (size_t)BL*DM;          // 2,097,152 elems
    const size_t CH  = (size_t)NCHUNK*NCHAIN;  // 1,048,576 floats
    _Float16* xnh = (_Float16*)d_ws;           // BL*DM f16
    float* dtb = (float*)(xnh + BSZ);          // BL*DM fp32
    float* Bmb = dtb + BSZ;
    float* Cmb = Bmb + (size_t)BL*NS;
    float* cA  = Cmb + (size_t)BL*NS;
    float* cB  = cA  + CH;
    float* hin = cB  + CH;
    _Float16* packs = (_Float16*)(hin + CH);
    _Float16* pd0 = packs;
    _Float16* pd1 = pd0 + 73728;
    _Float16* pm0 = pd1 + 73728;
    _Float16* pm1 = pm0 + 65536;

    pack_w_k<<<dim3(36,4), 256, 0, stream>>>(Wd, WB, WC, Wm, pd0, pm0, pd1, pm1);

    const float* A1  = A  + (size_t)DM*NS;
    const float* bd1 = bd + DM;
    const float* Ds1 = Ds + DM;
    const float* bm1 = bm + DM;

    dim3 gchunk(NCHUNK, BATCH);
    const int P2_BLOCKS = (NCHAIN/4)*SEG/256;   // 64

    // ---- layer 0: rmsnorm + dtbc GEMM + summaries ----
    fused_pre_s<<<BL/32, 576, 0, stream>>>(x, pd0, bd, A, xnh, dtb, Bmb, Cmb, cA, cB);
    scan_p2<<<P2_BLOCKS, 256, 0, stream>>>(cA, cB, hin);
    // ---- scan(L0) + mix(L0) + rmsnorm + dtbc(L1) + summaries(L1) ----
    scan_mid<<<gchunk, 1024, 0, stream>>>(xnh, dtb, Bmb, Cmb, A, Ds, hin,
                                          pm0, bm, pd1, bd1, A1, cA, cB);
    scan_p2<<<P2_BLOCKS, 256, 0, stream>>>(cA, cB, hin);
    // ---- scan(L1) + mix(L1) + final rmsnorm ----
    scan_out<<<gchunk, 1024, 0, stream>>>(xnh, dtb, Bmb, Cmb, A1, Ds1, hin,
                                          pm1, bm1, out);
}